// Round 13
// baseline (275.093 us; speedup 1.0000x reference)
//
#include <hip/hip_runtime.h>

#define NN 4096
#define DD 128
#define BB 128
#define QQ 5
#define MAXDEG 96
#define SRCF 0x40000000

typedef __attribute__((ext_vector_type(8))) short bf16x8;
typedef __attribute__((ext_vector_type(4))) float f32x4;

__device__ __forceinline__ float dot4f(float4 a, float4 b) {
    return a.x*b.x + a.y*b.y + a.z*b.z + a.w*b.w;
}
// round-to-nearest-even f32 -> bf16
__device__ __forceinline__ unsigned short bfr(float x) {
    unsigned u = __float_as_uint(x);
    return (unsigned short)((u + 0x7fffu + ((u >> 16) & 1u)) >> 16);
}
__device__ __forceinline__ unsigned int pack2bf(float lo, float hi) {
    return ((unsigned int)bfr(hi) << 16) | (unsigned int)bfr(lo);
}

// ---------------- neighbor-list precompute (parallel) ----------------
__global__ void nbr_kernel(const int* __restrict__ u, const int* __restrict__ v,
                           const float* __restrict__ A, const float* __restrict__ S,
                           int* __restrict__ nbr_cnt, int2* __restrict__ nbr_pack)
{
    __shared__ int   lcnt[257];
    __shared__ int   sidx[MAXDEG];
    __shared__ float sq[MAXDEG];
    __shared__ float ssum;
    __shared__ int   stot;

    const int p    = blockIdx.x;
    const int i    = p >> 1;
    const int side = p & 1;
    const int other = (side == 0) ? v[i] : u[i];
    const float* Arow = A + (size_t)other * NN;
    const float* Srow = S + (size_t)other * NN;
    const int tid = threadIdx.x;

    const int base = tid * 16;
    int c0 = 0;
    for (int j = 0; j < 16; ++j) c0 += (Arow[base + j] > 0.0f) ? 1 : 0;
    lcnt[tid] = c0;
    __syncthreads();
    if (tid == 0) {
        int s = 0;
        for (int k = 0; k < 256; ++k) { int c = lcnt[k]; lcnt[k] = s; s += c; }
        stot = s;
    }
    __syncthreads();
    int off = lcnt[tid];
    for (int j = 0; j < 16; ++j) {
        if (Arow[base + j] > 0.0f) {
            if (off < MAXDEG) sidx[off] = base + j;
            ++off;
        }
    }
    __syncthreads();
    int cnt = stot; if (cnt > MAXDEG) cnt = MAXDEG;
    for (int jj = tid; jj < cnt; jj += 256) sq[jj] = expf(Srow[sidx[jj]]);
    __syncthreads();
    if (tid == 0) {
        float s = 0.0f;
        for (int jj = 0; jj < cnt; ++jj) s += sq[jj];
        ssum = s + 1e-7f;
    }
    __syncthreads();
    for (int jj = tid; jj < cnt; jj += 256) {
        int2 pk;
        pk.x = sidx[jj];
        pk.y = __float_as_int(sq[jj] / ssum);
        nbr_pack[p * MAXDEG + jj] = pk;
    }
    if (tid == 0) nbr_cnt[p] = cnt;
}

// ---------------- Whz0[n][d] = z0[n].Wh[d] + bh[d] (parallel, f32 exact) ----------------
__global__ __launch_bounds__(512) void whz_init(
    const float* __restrict__ z0, const float* __restrict__ Wh, const float* __restrict__ bh,
    float* __restrict__ Whz0)
{
    const int t   = threadIdx.x;
    const int rep = t & 7;
    const int d0  = t >> 3;
    float4 wh0[4], wh1[4];
    #pragma unroll
    for (int m = 0; m < 4; ++m) {
        wh0[m] = *(const float4*)(Wh + (size_t)d0*DD + rep*16 + m*4);
        wh1[m] = *(const float4*)(Wh + (size_t)(d0+64)*DD + rep*16 + m*4);
    }
    const float bh0 = bh[d0], bh1 = bh[d0+64];
    const int r0 = blockIdx.x * 16;
    for (int r = r0; r < r0 + 16; ++r) {
        const float* zr = z0 + (size_t)r*DD + rep*16;
        float a0 = 0.f, a1 = 0.f;
        #pragma unroll
        for (int m = 0; m < 4; ++m) {
            float4 zz = *(const float4*)(zr + m*4);
            a0 += dot4f(zz, wh0[m]);
            a1 += dot4f(zz, wh1[m]);
        }
        a0 += __shfl_xor(a0,1); a0 += __shfl_xor(a0,2); a0 += __shfl_xor(a0,4);
        a1 += __shfl_xor(a1,1); a1 += __shfl_xor(a1,2); a1 += __shfl_xor(a1,4);
        if (rep == 0) {
            Whz0[(size_t)r*DD + d0]    = a0 + bh0;
            Whz0[(size_t)r*DD + d0+64] = a1 + bh1;
        }
    }
}

// ---------------- last-update sources for u,v,neg rows (parallel) ----------------
__global__ void src_kernel(const int* __restrict__ u, const int* __restrict__ v,
                           const int* __restrict__ neg,
                           int* __restrict__ zsrc, int* __restrict__ negsrc)
{
    const int i = blockIdx.x;
    const int k = threadIdx.x;
    if (k >= 2 + 2*QQ) return;
    const int n = (k == 0) ? u[i] : (k == 1) ? v[i] : neg[i*2*QQ + (k-2)];
    int s = n;
    for (int j = i-1; j >= 0; --j) {
        if (v[j] == n) { s = SRCF | (j*2 + 1); break; }
        if (u[j] == n) { s = SRCF | (j*2 + 0); break; }
    }
    if (k < 2) zsrc[i*2 + k] = s;
    else       negsrc[i*2*QQ + (k-2)] = s;
}

// ---------------- static-max + correction lists per (i,side) (parallel) ----------------
__global__ void prep_kernel(const int* __restrict__ u, const int* __restrict__ v,
                            const int* __restrict__ nbr_cnt, const int2* __restrict__ nbr_pack,
                            const float* __restrict__ Whz0,
                            float* __restrict__ maxpre, int* __restrict__ ncorr,
                            int2* __restrict__ corr_pack)
{
    __shared__ int   su[BB], sv[BB];
    __shared__ int   sidx[MAXDEG];
    __shared__ float sq[MAXDEG];
    __shared__ unsigned char cflag[MAXDEG];
    __shared__ int ccnt;

    const int p   = blockIdx.x;
    const int i   = p >> 1;
    const int tid = threadIdx.x;
    if (tid < BB) { su[tid] = u[tid]; sv[tid] = v[tid]; }
    if (tid == 0) ccnt = 0;
    const int cnt = nbr_cnt[p];
    for (int jj = tid; jj < cnt; jj += 128) {
        int2 pk = nbr_pack[p*MAXDEG + jj];
        sidx[jj] = pk.x; sq[jj] = __int_as_float(pk.y);
    }
    __syncthreads();
    for (int jj = tid; jj < cnt; jj += 128) {
        const int r = sidx[jj];
        int fs = -1;
        for (int j = i-1; j >= 0; --j) {
            if (sv[j] == r) { fs = j*2 + 1; break; }
            if (su[j] == r) { fs = j*2 + 0; break; }
        }
        if (fs >= 0) {
            const int pos = atomicAdd(&ccnt, 1);   // order-free (folded with commutative max)
            int2 cp; cp.x = fs; cp.y = __float_as_int(sq[jj]);
            corr_pack[p*MAXDEG + pos] = cp;
            cflag[jj] = 1;
        } else cflag[jj] = 0;
    }
    __syncthreads();
    const int d = tid;
    float m = -3.0e38f;
    for (int jj = 0; jj < cnt; ++jj)
        if (!cflag[jj]) m = fmaxf(m, sq[jj] * Whz0[(size_t)sidx[jj]*DD + d]);
    maxpre[(size_t)p*DD + d] = m;
    if (tid == 0) ncorr[p] = ccnt;
}

// ---------------- sequential scan: 1 block, 512 threads, rebalanced pipeline ----------------
// All step-(i+1) prep (h-gather fold, zu/zv select, tdw) happens in the P2 window,
// overlapped with the whz-GEMM. P0 only writes prefetched values + rare fixup for
// correction entries referencing the immediately-preceding step (<=2/side, provably).
__global__ __launch_bounds__(512) void scan_kernel(
    const float* __restrict__ z0, const float* __restrict__ time_diff,
    const int* __restrict__ nbr_cnt, const int* __restrict__ ncorr,
    const int2* __restrict__ corr_pack,
    const float* __restrict__ maxpre, const int* __restrict__ zsrc,
    const float* __restrict__ Wh,  const float* __restrict__ bh,
    const float* __restrict__ Wst, const float* __restrict__ bst,
    const float* __restrict__ Wrc, const float* __restrict__ brc,
    const float* __restrict__ Wt,  const float* __restrict__ bt,
    float* __restrict__ zlog)
{
    __shared__ __align__(16) unsigned short whz_sb[2*BB*DD];   // 64 KB whz log (bf16)
    __shared__ __align__(16) unsigned short zlog_sb[2*BB*DD];  // 64 KB z log (bf16)
    __shared__ __align__(16) unsigned short h_sb[2][DD];
    __shared__ __align__(16) unsigned short zub[DD];
    __shared__ __align__(16) unsigned short zvb[DD];
    __shared__ __align__(16) float zupd_s[2][DD];
    __shared__ __align__(16) unsigned short zupdb[2][DD];
    __shared__ __align__(16) float tdw_s[2][DD];
    __shared__ __align__(16) float tdi_s[BB*8];                // prescaled time_diff (4 KB)
    __shared__ int cnt_s[2*BB], ncorr_s[2*BB], zsrc_s[2*BB];

    const int t    = threadIdx.x;
    const int wv   = t >> 6;
    const int ln   = t & 63;
    const int arow = wv*16 + (ln & 15);
    const int kgrp = ln >> 4;
    const int ncol = ln & 15;
    const int dbase = wv*16 + kgrp*4;

    // ---- persistent A-fragments (packed bf16 -> remat-proof, r11-proven) ----
    bf16x8 afw[8];   // [Wst | Wrc], K=256
    #pragma unroll
    for (int kt = 0; kt < 8; ++kt) {
        const int kb = kt*32 + kgrp*8;
        const float* src = (kb < 128) ? (Wst + (size_t)arow*DD + kb)
                                      : (Wrc + (size_t)arow*DD + (kb - 128));
        #pragma unroll
        for (int j = 0; j < 8; ++j) afw[kt][j] = (short)bfr(src[j]);
    }
    bf16x8 afh[4];   // Wh, K=128
    #pragma unroll
    for (int kt = 0; kt < 4; ++kt) {
        const float* src = Wh + (size_t)arow*DD + kt*32 + kgrp*8;
        #pragma unroll
        for (int j = 0; j < 8; ++j) afh[kt][j] = (short)bfr(src[j]);
    }
    f32x4 bsv, bhv;
    #pragma unroll
    for (int r = 0; r < 4; ++r) {
        bsv[r] = bst[dbase+r] + brc[dbase+r] + bt[dbase+r];
        bhv[r] = bh[dbase+r];
    }
    const float4 wtA = *(const float4*)(Wt + (size_t)(ln*2)*4);
    const float4 wtB = *(const float4*)(Wt + (size_t)(ln*2+1)*4);

    // ---- one-time LDS preloads ----
    if (t < 256)      { cnt_s[t] = nbr_cnt[t]; ncorr_s[t] = ncorr[t]; }
    else              { zsrc_s[t-256] = zsrc[t-256]; }
    {
        const float sdv[4] = {50.f, 7.f, 15.f, 15.f};
        for (int e = t; e < BB*8; e += 512) tdi_s[e] = time_diff[e] / sdv[e & 3];
    }
    __syncthreads();

    // ---- per-wave pipeline registers ----
    float2 mnext = make_float2(0.f, 0.f);     // maxpre for step i+1 (wv0/1)
    int2 cpf0, cpf1, cpf2, cpf3;              // corr entries for step i+1 (wv0/1)
    float2 mwork = make_float2(0.f, 0.f);     // partial m when deferral pending
    int2 dc0, dc1; int ndef = 0;              // deferred entries (src step == i)
    float2 znextW = make_float2(0.f, 0.f);    // zu/zv value for step i+1 (wv2/3)
    float2 zn2    = make_float2(0.f, 0.f);    // prefetched z0 row for step i+2 (wv2/3)

    // ---- priming: prepare step 0 (acts as "P2a(-1)") ----
    if (wv <= 1) {
        const int side = wv;
        float2 m0 = *(const float2*)&maxpre[(size_t)side*DD + ln*2];
        float h0 = 0.f, h1 = 0.f;
        if (cnt_s[side] > 0) {                 // ncorr[step0] == 0 always
            h0 = 1.0f/(1.0f + __expf(-m0.x));
            h1 = 1.0f/(1.0f + __expf(-m0.y));
        }
        *(unsigned int*)&h_sb[side][ln*2] = pack2bf(h0, h1);
        mnext = *(const float2*)&maxpre[(size_t)(2+side)*DD + ln*2];
        const int2* cpp = corr_pack + (size_t)(2+side)*MAXDEG;
        cpf0 = cpp[0]; cpf1 = cpp[1]; cpf2 = cpp[2]; cpf3 = cpp[3];
    } else if (wv <= 3) {
        const int r2 = wv - 2;
        const int s = zsrc_s[r2];              // step 0: always a z0 row
        znextW = *(const float2*)&z0[(size_t)(s & 0xFFFF)*DD + ln*2];
        const int s1 = zsrc_s[2 + r2];
        if (!(s1 & SRCF)) zn2 = *(const float2*)&z0[(size_t)s1*DD + ln*2];
    } else if (wv == 4) {
        const float* td0 = &tdi_s[0];
        tdw_s[0][ln*2]   = td0[0]*wtA.x + td0[1]*wtA.y + td0[2]*wtA.z + td0[3]*wtA.w;
        tdw_s[0][ln*2+1] = td0[0]*wtB.x + td0[1]*wtB.y + td0[2]*wtB.z + td0[3]*wtB.w;
        tdw_s[1][ln*2]   = td0[4]*wtA.x + td0[5]*wtA.y + td0[6]*wtA.z + td0[7]*wtA.w;
        tdw_s[1][ln*2+1] = td0[4]*wtB.x + td0[5]*wtB.y + td0[6]*wtB.z + td0[7]*wtB.w;
    }

    for (int i = 0; i < BB; ++i) {
        // ================= P0: publish prefetched inputs (near-empty) =================
        if (wv <= 1) {
            if (ndef) {        // rare: fold entries referencing step i-1's rows
                float2 m = mwork;
                {
                    const float qc = __int_as_float(dc0.y);
                    const unsigned pk = *(const unsigned*)&whz_sb[dc0.x*DD + ln*2];
                    m.x = fmaxf(m.x, qc * __uint_as_float(pk << 16));
                    m.y = fmaxf(m.y, qc * __uint_as_float(pk & 0xffff0000u));
                }
                if (ndef > 1) {
                    const float qc = __int_as_float(dc1.y);
                    const unsigned pk = *(const unsigned*)&whz_sb[dc1.x*DD + ln*2];
                    m.x = fmaxf(m.x, qc * __uint_as_float(pk << 16));
                    m.y = fmaxf(m.y, qc * __uint_as_float(pk & 0xffff0000u));
                }
                float h0 = 0.f, h1 = 0.f;
                if (cnt_s[i*2 + wv] > 0) {
                    h0 = 1.0f/(1.0f + __expf(-m.x));
                    h1 = 1.0f/(1.0f + __expf(-m.y));
                }
                *(unsigned int*)&h_sb[wv][ln*2] = pack2bf(h0, h1);
                ndef = 0;
            }
        } else if (wv <= 3) {
            unsigned short* dst = (wv == 3) ? zvb : zub;
            *(unsigned int*)&dst[ln*2] = pack2bf(znextW.x, znextW.y);
        }
        __syncthreads();   // B1

        // ================= P1: z_upd GEMM (K=256, 2 acc chains) =================
        {
            const int cc = (ncol < 2) ? ncol : 0;
            const unsigned short* hp = &h_sb[cc][0];
            const unsigned short* zp = cc ? zvb : zub;
            f32x4 accA = {0.f,0.f,0.f,0.f}, accB = {0.f,0.f,0.f,0.f};
            #pragma unroll
            for (int kt = 0; kt < 4; kt += 2) {
                bf16x8 b0 = *(const bf16x8*)&hp[kt*32 + kgrp*8];
                bf16x8 b1 = *(const bf16x8*)&hp[(kt+1)*32 + kgrp*8];
                accA = __builtin_amdgcn_mfma_f32_16x16x32_bf16(afw[kt],   b0, accA, 0,0,0);
                accB = __builtin_amdgcn_mfma_f32_16x16x32_bf16(afw[kt+1], b1, accB, 0,0,0);
            }
            #pragma unroll
            for (int kt = 4; kt < 8; kt += 2) {
                bf16x8 b0 = *(const bf16x8*)&zp[(kt-4)*32 + kgrp*8];
                bf16x8 b1 = *(const bf16x8*)&zp[(kt-3)*32 + kgrp*8];
                accA = __builtin_amdgcn_mfma_f32_16x16x32_bf16(afw[kt],   b0, accA, 0,0,0);
                accB = __builtin_amdgcn_mfma_f32_16x16x32_bf16(afw[kt+1], b1, accB, 0,0,0);
            }
            if (ncol < 2) {
                const f32x4 tdwv = *(const f32x4*)&tdw_s[ncol][dbase];
                f32x4 zu4;
                #pragma unroll
                for (int r = 0; r < 4; ++r) {
                    const float a = accA[r] + accB[r] + bsv[r] + tdwv[r];
                    zu4[r] = 1.0f/(1.0f + __expf(-a));
                }
                *(f32x4*)&zupd_s[ncol][dbase] = zu4;
                uint2 pk;
                pk.x = pack2bf(zu4[0], zu4[1]);
                pk.y = pack2bf(zu4[2], zu4[3]);
                *(uint2*)&zupdb[ncol][dbase] = pk;
            }
        }
        __syncthreads();   // B2

        // ================= P2: whz GEMM + ALL step-(i+1) prep (overlapped) =================
        // P2b: whz of this step's updates
        {
            const int cc = (ncol < 2) ? ncol : 0;
            const unsigned short* up = &zupdb[cc][0];
            f32x4 accA = {0.f,0.f,0.f,0.f}, accB = {0.f,0.f,0.f,0.f};
            {
                bf16x8 b0 = *(const bf16x8*)&up[0*32 + kgrp*8];
                bf16x8 b1 = *(const bf16x8*)&up[1*32 + kgrp*8];
                bf16x8 b2 = *(const bf16x8*)&up[2*32 + kgrp*8];
                bf16x8 b3 = *(const bf16x8*)&up[3*32 + kgrp*8];
                accA = __builtin_amdgcn_mfma_f32_16x16x32_bf16(afh[0], b0, accA, 0,0,0);
                accB = __builtin_amdgcn_mfma_f32_16x16x32_bf16(afh[1], b1, accB, 0,0,0);
                accA = __builtin_amdgcn_mfma_f32_16x16x32_bf16(afh[2], b2, accA, 0,0,0);
                accB = __builtin_amdgcn_mfma_f32_16x16x32_bf16(afh[3], b3, accB, 0,0,0);
            }
            if (ncol < 2) {
                const int row = i*2 + ncol;
                uint2 wpk;
                wpk.x = pack2bf(accA[0]+accB[0]+bhv[0], accA[1]+accB[1]+bhv[1]);
                wpk.y = pack2bf(accA[2]+accB[2]+bhv[2], accA[3]+accB[3]+bhv[3]);
                *(uint2*)&whz_sb[row*DD + dbase] = wpk;
                const f32x4 zu4 = *(const f32x4*)&zupd_s[ncol][dbase];
                uint2 zpk;
                zpk.x = pack2bf(zu4[0], zu4[1]);
                zpk.y = pack2bf(zu4[2], zu4[3]);
                *(uint2*)&zlog_sb[row*DD + dbase] = zpk;
                *(f32x4*)&zlog[(size_t)row*DD + dbase] = zu4;   // fire-and-forget
            }
        }
        // P2a: prepare step i+1 (waves 0-4), overlapping the GEMM above
        if (i + 1 < BB) {
            if (wv <= 1) {
                const int side = wv;
                const int p1 = (i+1)*2 + side;
                const int nc = ncorr_s[p1];
                float2 m = mnext;
                int nd = 0; int2 d0, d1;
                auto FOLD = [&](int2 e) {
                    if ((e.x >> 1) == i) { if (nd == 0) d0 = e; else d1 = e; ++nd; }
                    else {
                        const float qc = __int_as_float(e.y);
                        const unsigned pk = *(const unsigned*)&whz_sb[e.x*DD + ln*2];
                        m.x = fmaxf(m.x, qc * __uint_as_float(pk << 16));
                        m.y = fmaxf(m.y, qc * __uint_as_float(pk & 0xffff0000u));
                    }
                };
                if (nc > 0) FOLD(cpf0);
                if (nc > 1) FOLD(cpf1);
                if (nc > 2) FOLD(cpf2);
                if (nc > 3) FOLD(cpf3);
                const int2* cpp = corr_pack + (size_t)p1*MAXDEG;
                for (int c = 4; c < nc; ++c) FOLD(cpp[c]);
                if (nd == 0) {
                    float h0 = 0.f, h1 = 0.f;
                    if (cnt_s[p1] > 0) {
                        h0 = 1.0f/(1.0f + __expf(-m.x));
                        h1 = 1.0f/(1.0f + __expf(-m.y));
                    }
                    *(unsigned int*)&h_sb[side][ln*2] = pack2bf(h0, h1);
                } else {
                    mwork = m; dc0 = d0; dc1 = d1;
                }
                ndef = nd;
                // prefetch step i+2 inputs (drained at B3, ~fully landed by use)
                const int pn = ((i+2 < BB) ? (i+2) : (BB-1))*2 + side;
                mnext = *(const float2*)&maxpre[(size_t)pn*DD + ln*2];
                const int2* cppn = corr_pack + (size_t)pn*MAXDEG;
                cpf0 = cppn[0]; cpf1 = cppn[1]; cpf2 = cppn[2]; cpf3 = cppn[3];
            } else if (wv <= 3) {
                const int r2 = wv - 2;
                const int s = zsrc_s[(i+1)*2 + r2];
                if (s & SRCF) {
                    const int row = s & 0xFFFF;
                    if ((row >> 1) == i) {
                        znextW = *(const float2*)&zupd_s[row & 1][ln*2];
                    } else {
                        const unsigned pk = *(const unsigned*)&zlog_sb[row*DD + ln*2];
                        znextW.x = __uint_as_float(pk << 16);
                        znextW.y = __uint_as_float(pk & 0xffff0000u);
                    }
                } else {
                    znextW = zn2;                     // prefetched last step
                }
                const int i2 = (i+2 < BB) ? (i+2) : (BB-1);
                const int s2 = zsrc_s[i2*2 + r2];
                if (!(s2 & SRCF)) zn2 = *(const float2*)&z0[(size_t)s2*DD + ln*2];
            } else if (wv == 4) {
                const float* tdp = &tdi_s[(i+1)*8];
                tdw_s[0][ln*2]   = tdp[0]*wtA.x + tdp[1]*wtA.y + tdp[2]*wtA.z + tdp[3]*wtA.w;
                tdw_s[0][ln*2+1] = tdp[0]*wtB.x + tdp[1]*wtB.y + tdp[2]*wtB.z + tdp[3]*wtB.w;
                tdw_s[1][ln*2]   = tdp[4]*wtA.x + tdp[5]*wtA.y + tdp[6]*wtA.z + tdp[7]*wtA.w;
                tdw_s[1][ln*2+1] = tdp[4]*wtB.x + tdp[5]*wtB.y + tdp[6]*wtB.z + tdp[7]*wtB.w;
            }
        }
        __syncthreads();   // B3
    }
}

// ---------------- intensity epilogue (parallel, reads via src indices) ----------------
__global__ void lam_kernel(const float* __restrict__ z0, const float* __restrict__ zlog,
                           const int* __restrict__ zsrc, const int* __restrict__ negsrc,
                           const int* __restrict__ et,
                           const float* __restrict__ w0, const float* __restrict__ b0,
                           const float* __restrict__ w1, const float* __restrict__ b1,
                           const float* __restrict__ psi,
                           float* __restrict__ out)
{
    const int b   = blockIdx.x;
    const int i   = b / 11;
    const int col = b % 11;
    const int l   = threadIdx.x;

    auto rp = [&](int s) -> const float* {
        return (s & SRCF) ? (zlog + (size_t)(s & 0xFFFF)*DD) : (z0 + (size_t)s*DD);
    };
    const float* xu;
    const float* xv;
    if (col == 0) { xu = rp(zsrc[i*2]); xv = rp(zsrc[i*2+1]); }
    else {
        const int k = col - 1;
        xu = (k < QQ) ? rp(zsrc[i*2])            : rp(negsrc[i*2*QQ + k]);
        xv = (k < QQ) ? rp(negsrc[i*2*QQ + k])   : rp(zsrc[i*2+1]);
    }
    float g0 = xu[l]*w0[l] + xu[l+64]*w0[l+64] + xv[l]*w0[DD+l] + xv[l+64]*w0[DD+l+64];
    float g1 = xu[l]*w1[l] + xu[l+64]*w1[l+64] + xv[l]*w1[DD+l] + xv[l+64]*w1[DD+l+64];
    #pragma unroll
    for (int s = 32; s >= 1; s >>= 1) { g0 += __shfl_xor(g0, s); g1 += __shfl_xor(g1, s); }
    if (l == 0) {
        g0 += b0[0]; g1 += b1[0];
        const float p0 = psi[0], p1 = psi[1];
        float r;
        if (col == 0) {
            const int e = et[i];
            const float g = e ? g1 : g0;
            const float p = e ? p1 : p0;
            const float y = g / (p + 1e-7f);
            r = p * (fmaxf(y, 0.f) + log1pf(expf(-fabsf(y))));
        } else {
            const float y0 = g0 / (p0 + 1e-7f);
            const float y1 = g1 / (p1 + 1e-7f);
            r = p0 * (fmaxf(y0, 0.f) + log1pf(expf(-fabsf(y0))))
              + p1 * (fmaxf(y1, 0.f) + log1pf(expf(-fabsf(y1))));
        }
        out[i*11 + col] = r;
    }
}

extern "C" void kernel_launch(void* const* d_in, const int* in_sizes, int n_in,
                              void* d_out, int out_size, void* d_ws, size_t ws_size,
                              hipStream_t stream)
{
    const int*   u   = (const int*)d_in[0];
    const int*   v   = (const int*)d_in[1];
    const int*   et  = (const int*)d_in[2];
    const float* td  = (const float*)d_in[3];
    const int*   neg = (const int*)d_in[4];
    const float* z0  = (const float*)d_in[5];
    const float* A   = (const float*)d_in[6];
    const float* S   = (const float*)d_in[7];
    const float* w0  = (const float*)d_in[8];
    const float* b0  = (const float*)d_in[9];
    const float* w1  = (const float*)d_in[10];
    const float* b1  = (const float*)d_in[11];
    const float* psi = (const float*)d_in[12];
    const float* Wh  = (const float*)d_in[13];
    const float* bh  = (const float*)d_in[14];
    const float* Wst = (const float*)d_in[15];
    const float* bst = (const float*)d_in[16];
    const float* Wrc = (const float*)d_in[17];
    const float* brc = (const float*)d_in[18];
    const float* Wt  = (const float*)d_in[19];
    const float* bt  = (const float*)d_in[20];

    char* ws = (char*)d_ws;
    size_t off = 0;
    auto alloc = [&](size_t bytes) {
        void* p = ws + off;
        off = (off + bytes + 255) & ~(size_t)255;
        return p;
    };
    float* Whz0   = (float*)alloc((size_t)NN*DD*sizeof(float));
    float* maxpre = (float*)alloc((size_t)2*BB*DD*sizeof(float));
    float* zlog   = (float*)alloc((size_t)2*BB*DD*sizeof(float));
    int*   ncnt   = (int*)alloc((size_t)2*BB*sizeof(int));
    int*   ncorr  = (int*)alloc((size_t)2*BB*sizeof(int));
    int2*  cpk    = (int2*)alloc((size_t)2*BB*MAXDEG*sizeof(int2));
    int*   zsrc   = (int*)alloc((size_t)2*BB*sizeof(int));
    int*   negsrc = (int*)alloc((size_t)BB*2*QQ*sizeof(int));
    int2*  npk    = (int2*)alloc((size_t)2*BB*MAXDEG*sizeof(int2));

    whz_init<<<NN/16, 512, 0, stream>>>(z0, Wh, bh, Whz0);
    nbr_kernel<<<2*BB, 256, 0, stream>>>(u, v, A, S, ncnt, npk);
    src_kernel<<<BB, 64, 0, stream>>>(u, v, neg, zsrc, negsrc);
    prep_kernel<<<2*BB, 128, 0, stream>>>(u, v, ncnt, npk, Whz0, maxpre, ncorr, cpk);
    scan_kernel<<<1, 512, 0, stream>>>(z0, td, ncnt, ncorr, cpk, maxpre, zsrc,
                                       Wh, bh, Wst, bst, Wrc, brc, Wt, bt, zlog);
    lam_kernel<<<BB*(1 + 2*QQ), 64, 0, stream>>>(z0, zlog, zsrc, negsrc, et,
                                                 w0, b0, w1, b1, psi, (float*)d_out);
}

// Round 14
// 260.773 us; speedup vs baseline: 1.0549x; 1.0549x over previous
//
#include <hip/hip_runtime.h>

#define NN 4096
#define DD 128
#define BB 128
#define QQ 5
#define MAXDEG 96
#define SRCF 0x40000000

typedef __attribute__((ext_vector_type(8))) short bf16x8;
typedef __attribute__((ext_vector_type(4))) float f32x4;

// LDS-only barrier: order our ds ops, sync waves, never drain vmcnt.
#define LBAR() do { asm volatile("s_waitcnt lgkmcnt(0)" ::: "memory"); \
                    __builtin_amdgcn_sched_barrier(0); \
                    __builtin_amdgcn_s_barrier(); \
                    __builtin_amdgcn_sched_barrier(0); } while (0)

__device__ __forceinline__ float dot4f(float4 a, float4 b) {
    return a.x*b.x + a.y*b.y + a.z*b.z + a.w*b.w;
}
// round-to-nearest-even f32 -> bf16
__device__ __forceinline__ unsigned short bfr(float x) {
    unsigned u = __float_as_uint(x);
    return (unsigned short)((u + 0x7fffu + ((u >> 16) & 1u)) >> 16);
}
__device__ __forceinline__ unsigned int pack2bf(float lo, float hi) {
    return ((unsigned int)bfr(hi) << 16) | (unsigned int)bfr(lo);
}

// ---------------- neighbor-list precompute (parallel) ----------------
__global__ void nbr_kernel(const int* __restrict__ u, const int* __restrict__ v,
                           const float* __restrict__ A, const float* __restrict__ S,
                           int* __restrict__ nbr_cnt, int2* __restrict__ nbr_pack)
{
    __shared__ int   lcnt[257];
    __shared__ int   sidx[MAXDEG];
    __shared__ float sq[MAXDEG];
    __shared__ float ssum;
    __shared__ int   stot;

    const int p    = blockIdx.x;
    const int i    = p >> 1;
    const int side = p & 1;
    const int other = (side == 0) ? v[i] : u[i];
    const float* Arow = A + (size_t)other * NN;
    const float* Srow = S + (size_t)other * NN;
    const int tid = threadIdx.x;

    const int base = tid * 16;
    int c0 = 0;
    for (int j = 0; j < 16; ++j) c0 += (Arow[base + j] > 0.0f) ? 1 : 0;
    lcnt[tid] = c0;
    __syncthreads();
    if (tid == 0) {
        int s = 0;
        for (int k = 0; k < 256; ++k) { int c = lcnt[k]; lcnt[k] = s; s += c; }
        stot = s;
    }
    __syncthreads();
    int off = lcnt[tid];
    for (int j = 0; j < 16; ++j) {
        if (Arow[base + j] > 0.0f) {
            if (off < MAXDEG) sidx[off] = base + j;
            ++off;
        }
    }
    __syncthreads();
    int cnt = stot; if (cnt > MAXDEG) cnt = MAXDEG;
    for (int jj = tid; jj < cnt; jj += 256) sq[jj] = expf(Srow[sidx[jj]]);
    __syncthreads();
    if (tid == 0) {
        float s = 0.0f;
        for (int jj = 0; jj < cnt; ++jj) s += sq[jj];
        ssum = s + 1e-7f;
    }
    __syncthreads();
    for (int jj = tid; jj < cnt; jj += 256) {
        int2 pk;
        pk.x = sidx[jj];
        pk.y = __float_as_int(sq[jj] / ssum);
        nbr_pack[p * MAXDEG + jj] = pk;
    }
    if (tid == 0) nbr_cnt[p] = cnt;
}

// ---------------- Whz0[n][d] = z0[n].Wh[d] + bh[d] (parallel, f32 exact) ----------------
__global__ __launch_bounds__(512) void whz_init(
    const float* __restrict__ z0, const float* __restrict__ Wh, const float* __restrict__ bh,
    float* __restrict__ Whz0)
{
    const int t   = threadIdx.x;
    const int rep = t & 7;
    const int d0  = t >> 3;
    float4 wh0[4], wh1[4];
    #pragma unroll
    for (int m = 0; m < 4; ++m) {
        wh0[m] = *(const float4*)(Wh + (size_t)d0*DD + rep*16 + m*4);
        wh1[m] = *(const float4*)(Wh + (size_t)(d0+64)*DD + rep*16 + m*4);
    }
    const float bh0 = bh[d0], bh1 = bh[d0+64];
    const int r0 = blockIdx.x * 16;
    for (int r = r0; r < r0 + 16; ++r) {
        const float* zr = z0 + (size_t)r*DD + rep*16;
        float a0 = 0.f, a1 = 0.f;
        #pragma unroll
        for (int m = 0; m < 4; ++m) {
            float4 zz = *(const float4*)(zr + m*4);
            a0 += dot4f(zz, wh0[m]);
            a1 += dot4f(zz, wh1[m]);
        }
        a0 += __shfl_xor(a0,1); a0 += __shfl_xor(a0,2); a0 += __shfl_xor(a0,4);
        a1 += __shfl_xor(a1,1); a1 += __shfl_xor(a1,2); a1 += __shfl_xor(a1,4);
        if (rep == 0) {
            Whz0[(size_t)r*DD + d0]    = a0 + bh0;
            Whz0[(size_t)r*DD + d0+64] = a1 + bh1;
        }
    }
}

// ---------------- last-update sources for u,v,neg rows (parallel) ----------------
__global__ void src_kernel(const int* __restrict__ u, const int* __restrict__ v,
                           const int* __restrict__ neg,
                           int* __restrict__ zsrc, int* __restrict__ negsrc)
{
    const int i = blockIdx.x;
    const int k = threadIdx.x;
    if (k >= 2 + 2*QQ) return;
    const int n = (k == 0) ? u[i] : (k == 1) ? v[i] : neg[i*2*QQ + (k-2)];
    int s = n;
    for (int j = i-1; j >= 0; --j) {
        if (v[j] == n) { s = SRCF | (j*2 + 1); break; }
        if (u[j] == n) { s = SRCF | (j*2 + 0); break; }
    }
    if (k < 2) zsrc[i*2 + k] = s;
    else       negsrc[i*2*QQ + (k-2)] = s;
}

// ---------------- static-max + correction lists per (i,side) (parallel) ----------------
__global__ void prep_kernel(const int* __restrict__ u, const int* __restrict__ v,
                            const int* __restrict__ nbr_cnt, const int2* __restrict__ nbr_pack,
                            const float* __restrict__ Whz0,
                            float* __restrict__ maxpre, int* __restrict__ ncorr,
                            int2* __restrict__ corr_pack)
{
    __shared__ int   su[BB], sv[BB];
    __shared__ int   sidx[MAXDEG];
    __shared__ float sq[MAXDEG];
    __shared__ unsigned char cflag[MAXDEG];
    __shared__ int ccnt;

    const int p   = blockIdx.x;
    const int i   = p >> 1;
    const int tid = threadIdx.x;
    if (tid < BB) { su[tid] = u[tid]; sv[tid] = v[tid]; }
    if (tid == 0) ccnt = 0;
    const int cnt = nbr_cnt[p];
    for (int jj = tid; jj < cnt; jj += 128) {
        int2 pk = nbr_pack[p*MAXDEG + jj];
        sidx[jj] = pk.x; sq[jj] = __int_as_float(pk.y);
    }
    __syncthreads();
    for (int jj = tid; jj < cnt; jj += 128) {
        const int r = sidx[jj];
        int fs = -1;
        for (int j = i-1; j >= 0; --j) {
            if (sv[j] == r) { fs = j*2 + 1; break; }
            if (su[j] == r) { fs = j*2 + 0; break; }
        }
        if (fs >= 0) {
            const int pos = atomicAdd(&ccnt, 1);   // order-free (folded with commutative max)
            int2 cp; cp.x = fs; cp.y = __float_as_int(sq[jj]);
            corr_pack[p*MAXDEG + pos] = cp;
            cflag[jj] = 1;
        } else cflag[jj] = 0;
    }
    __syncthreads();
    const int d = tid;
    float m = -3.0e38f;
    for (int jj = 0; jj < cnt; ++jj)
        if (!cflag[jj]) m = fmaxf(m, sq[jj] * Whz0[(size_t)sidx[jj]*DD + d]);
    maxpre[(size_t)p*DD + d] = m;
    if (tid == 0) ncorr[p] = ccnt;
}

// ---------------- sequential scan: 1 block, 512 threads, 2 LDS-barriers/step ----------------
// No in-loop global stores; no vmcnt drains (LBAR = lgkmcnt-only barrier).
// P2a prepares EVERYTHING for step i+1 (h fold, zu/zv publish, tdw); rare deferred
// corrections (src step == i, <=2/side) handled in a flag-gated fixup mini-phase.
__global__ __launch_bounds__(512) void scan_kernel(
    const float* __restrict__ z0, const float* __restrict__ time_diff,
    const int* __restrict__ nbr_cnt, const int* __restrict__ ncorr,
    const int2* __restrict__ corr_pack,
    const float* __restrict__ maxpre, const int* __restrict__ zsrc,
    const float* __restrict__ Wh,  const float* __restrict__ bh,
    const float* __restrict__ Wst, const float* __restrict__ bst,
    const float* __restrict__ Wrc, const float* __restrict__ brc,
    const float* __restrict__ Wt,  const float* __restrict__ bt,
    float* __restrict__ zlog)
{
    __shared__ __align__(16) unsigned short whz_sb[2*BB*DD];   // 64 KB whz log (bf16)
    __shared__ __align__(16) unsigned short zlog_sb[2*BB*DD];  // 64 KB z log (bf16)
    __shared__ __align__(16) unsigned short h_sb[2][DD];
    __shared__ __align__(16) unsigned short zub[DD];
    __shared__ __align__(16) unsigned short zvb[DD];
    __shared__ __align__(16) float zupd_s[2][DD];
    __shared__ __align__(16) unsigned short zupdb[2][DD];
    __shared__ __align__(16) float tdw_s[2][DD];
    __shared__ __align__(16) float tdi_s[BB*8];                // prescaled time_diff (4 KB)
    __shared__ int cnt_s[2*BB], ncorr_s[2*BB], zsrc_s[2*BB];
    __shared__ int defflag[2];

    const int t    = threadIdx.x;
    const int wv   = t >> 6;
    const int ln   = t & 63;
    const int arow = wv*16 + (ln & 15);
    const int kgrp = ln >> 4;
    const int ncol = ln & 15;
    const int dbase = wv*16 + kgrp*4;

    // ---- persistent A-fragments (packed bf16 -> remat-proof, r11-proven) ----
    bf16x8 afw[8];   // [Wst | Wrc], K=256
    #pragma unroll
    for (int kt = 0; kt < 8; ++kt) {
        const int kb = kt*32 + kgrp*8;
        const float* src = (kb < 128) ? (Wst + (size_t)arow*DD + kb)
                                      : (Wrc + (size_t)arow*DD + (kb - 128));
        #pragma unroll
        for (int j = 0; j < 8; ++j) afw[kt][j] = (short)bfr(src[j]);
    }
    bf16x8 afh[4];   // Wh, K=128
    #pragma unroll
    for (int kt = 0; kt < 4; ++kt) {
        const float* src = Wh + (size_t)arow*DD + kt*32 + kgrp*8;
        #pragma unroll
        for (int j = 0; j < 8; ++j) afh[kt][j] = (short)bfr(src[j]);
    }
    f32x4 bsv, bhv;
    #pragma unroll
    for (int r = 0; r < 4; ++r) {
        bsv[r] = bst[dbase+r] + brc[dbase+r] + bt[dbase+r];
        bhv[r] = bh[dbase+r];
    }
    const float4 wtA = *(const float4*)(Wt + (size_t)(ln*2)*4);
    const float4 wtB = *(const float4*)(Wt + (size_t)(ln*2+1)*4);

    // ---- one-time LDS preloads ----
    if (t < 256)      { cnt_s[t] = nbr_cnt[t]; ncorr_s[t] = ncorr[t]; }
    else              { zsrc_s[t-256] = zsrc[t-256]; }
    if (t < 2) defflag[t] = 0;
    {
        const float sdv[4] = {50.f, 7.f, 15.f, 15.f};
        for (int e = t; e < BB*8; e += 512) tdi_s[e] = time_diff[e] / sdv[e & 3];
    }
    __syncthreads();

    // ---- per-wave pipeline registers ----
    float2 mnext = make_float2(0.f, 0.f);
    int2 cpf0, cpf1, cpf2, cpf3;
    float2 mwork = make_float2(0.f, 0.f);
    int2 dc0, dc1; int ndef = 0;
    float2 zn2 = make_float2(0.f, 0.f);

    // ---- priming: prepare step 0 in full ("P2a(-1)") ----
    if (wv <= 1) {
        const int side = wv;
        float2 m0 = *(const float2*)&maxpre[(size_t)side*DD + ln*2];
        float h0 = 0.f, h1 = 0.f;
        if (cnt_s[side] > 0) {                 // ncorr[step0] == 0 always
            h0 = 1.0f/(1.0f + __expf(-m0.x));
            h1 = 1.0f/(1.0f + __expf(-m0.y));
        }
        *(unsigned int*)&h_sb[side][ln*2] = pack2bf(h0, h1);
        mnext = *(const float2*)&maxpre[(size_t)(2+side)*DD + ln*2];
        const int2* cpp = corr_pack + (size_t)(2+side)*MAXDEG;
        cpf0 = cpp[0]; cpf1 = cpp[1]; cpf2 = cpp[2]; cpf3 = cpp[3];
    } else if (wv <= 3) {
        const int r2 = wv - 2;
        const int s = zsrc_s[r2];              // step 0: always a z0 row
        const float2 zv0 = *(const float2*)&z0[(size_t)(s & 0xFFFF)*DD + ln*2];
        unsigned short* dst = (wv == 3) ? zvb : zub;
        *(unsigned int*)&dst[ln*2] = pack2bf(zv0.x, zv0.y);
        const int s1 = zsrc_s[2 + r2];
        if (!(s1 & SRCF)) zn2 = *(const float2*)&z0[(size_t)s1*DD + ln*2];
    } else if (wv == 4) {
        const float* td0 = &tdi_s[0];
        tdw_s[0][ln*2]   = td0[0]*wtA.x + td0[1]*wtA.y + td0[2]*wtA.z + td0[3]*wtA.w;
        tdw_s[0][ln*2+1] = td0[0]*wtB.x + td0[1]*wtB.y + td0[2]*wtB.z + td0[3]*wtB.w;
        tdw_s[1][ln*2]   = td0[4]*wtA.x + td0[5]*wtA.y + td0[6]*wtA.z + td0[7]*wtA.w;
        tdw_s[1][ln*2+1] = td0[4]*wtB.x + td0[5]*wtB.y + td0[6]*wtB.z + td0[7]*wtB.w;
    }
    LBAR();

    for (int i = 0; i < BB; ++i) {
        // ---- rare fixup phase: deferred corrections from step i-1's whz ----
        if (defflag[0] | defflag[1]) {
            if (wv <= 1 && ndef) {
                float2 m = mwork;
                {
                    const float qc = __int_as_float(dc0.y);
                    const unsigned pk = *(const unsigned*)&whz_sb[dc0.x*DD + ln*2];
                    m.x = fmaxf(m.x, qc * __uint_as_float(pk << 16));
                    m.y = fmaxf(m.y, qc * __uint_as_float(pk & 0xffff0000u));
                }
                if (ndef > 1) {
                    const float qc = __int_as_float(dc1.y);
                    const unsigned pk = *(const unsigned*)&whz_sb[dc1.x*DD + ln*2];
                    m.x = fmaxf(m.x, qc * __uint_as_float(pk << 16));
                    m.y = fmaxf(m.y, qc * __uint_as_float(pk & 0xffff0000u));
                }
                float h0 = 0.f, h1 = 0.f;
                if (cnt_s[i*2 + wv] > 0) {
                    h0 = 1.0f/(1.0f + __expf(-m.x));
                    h1 = 1.0f/(1.0f + __expf(-m.y));
                }
                *(unsigned int*)&h_sb[wv][ln*2] = pack2bf(h0, h1);
            }
            ndef = 0;
            LBAR();
        }

        // ================= P1: z_upd GEMM (K=256, 2 acc chains) =================
        {
            const int cc = (ncol < 2) ? ncol : 0;
            const unsigned short* hp = &h_sb[cc][0];
            const unsigned short* zp = cc ? zvb : zub;
            f32x4 accA = {0.f,0.f,0.f,0.f}, accB = {0.f,0.f,0.f,0.f};
            #pragma unroll
            for (int kt = 0; kt < 4; kt += 2) {
                bf16x8 b0 = *(const bf16x8*)&hp[kt*32 + kgrp*8];
                bf16x8 b1 = *(const bf16x8*)&hp[(kt+1)*32 + kgrp*8];
                accA = __builtin_amdgcn_mfma_f32_16x16x32_bf16(afw[kt],   b0, accA, 0,0,0);
                accB = __builtin_amdgcn_mfma_f32_16x16x32_bf16(afw[kt+1], b1, accB, 0,0,0);
            }
            #pragma unroll
            for (int kt = 4; kt < 8; kt += 2) {
                bf16x8 b0 = *(const bf16x8*)&zp[(kt-4)*32 + kgrp*8];
                bf16x8 b1 = *(const bf16x8*)&zp[(kt-3)*32 + kgrp*8];
                accA = __builtin_amdgcn_mfma_f32_16x16x32_bf16(afw[kt],   b0, accA, 0,0,0);
                accB = __builtin_amdgcn_mfma_f32_16x16x32_bf16(afw[kt+1], b1, accB, 0,0,0);
            }
            if (ncol < 2) {
                const f32x4 tdwv = *(const f32x4*)&tdw_s[ncol][dbase];
                f32x4 zu4;
                #pragma unroll
                for (int r = 0; r < 4; ++r) {
                    const float a = accA[r] + accB[r] + bsv[r] + tdwv[r];
                    zu4[r] = 1.0f/(1.0f + __expf(-a));
                }
                *(f32x4*)&zupd_s[ncol][dbase] = zu4;
                uint2 pk;
                pk.x = pack2bf(zu4[0], zu4[1]);
                pk.y = pack2bf(zu4[2], zu4[3]);
                *(uint2*)&zupdb[ncol][dbase] = pk;
            }
        }
        LBAR();   // B2

        // ================= P2: whz GEMM + ALL step-(i+1) prep (overlapped) =================
        {
            const int cc = (ncol < 2) ? ncol : 0;
            const unsigned short* up = &zupdb[cc][0];
            f32x4 accA = {0.f,0.f,0.f,0.f}, accB = {0.f,0.f,0.f,0.f};
            {
                bf16x8 b0 = *(const bf16x8*)&up[0*32 + kgrp*8];
                bf16x8 b1 = *(const bf16x8*)&up[1*32 + kgrp*8];
                bf16x8 b2 = *(const bf16x8*)&up[2*32 + kgrp*8];
                bf16x8 b3 = *(const bf16x8*)&up[3*32 + kgrp*8];
                accA = __builtin_amdgcn_mfma_f32_16x16x32_bf16(afh[0], b0, accA, 0,0,0);
                accB = __builtin_amdgcn_mfma_f32_16x16x32_bf16(afh[1], b1, accB, 0,0,0);
                accA = __builtin_amdgcn_mfma_f32_16x16x32_bf16(afh[2], b2, accA, 0,0,0);
                accB = __builtin_amdgcn_mfma_f32_16x16x32_bf16(afh[3], b3, accB, 0,0,0);
            }
            if (ncol < 2) {
                const int row = i*2 + ncol;
                uint2 wpk;
                wpk.x = pack2bf(accA[0]+accB[0]+bhv[0], accA[1]+accB[1]+bhv[1]);
                wpk.y = pack2bf(accA[2]+accB[2]+bhv[2], accA[3]+accB[3]+bhv[3]);
                *(uint2*)&whz_sb[row*DD + dbase] = wpk;
                const f32x4 zu4 = *(const f32x4*)&zupd_s[ncol][dbase];
                uint2 zpk;
                zpk.x = pack2bf(zu4[0], zu4[1]);
                zpk.y = pack2bf(zu4[2], zu4[3]);
                *(uint2*)&zlog_sb[row*DD + dbase] = zpk;
            }
        }
        // P2a: prepare step i+1 (waves 0-4), overlapping the GEMM above
        if (i + 1 < BB) {
            if (wv <= 1) {
                const int side = wv;
                const int p1 = (i+1)*2 + side;
                const int nc = ncorr_s[p1];
                float2 m = mnext;
                int nd = 0; int2 d0, d1;
                auto FOLD = [&](int2 e) {
                    if ((e.x >> 1) == i) { if (nd == 0) d0 = e; else d1 = e; ++nd; }
                    else {
                        const float qc = __int_as_float(e.y);
                        const unsigned pk = *(const unsigned*)&whz_sb[e.x*DD + ln*2];
                        m.x = fmaxf(m.x, qc * __uint_as_float(pk << 16));
                        m.y = fmaxf(m.y, qc * __uint_as_float(pk & 0xffff0000u));
                    }
                };
                if (nc > 0) FOLD(cpf0);
                if (nc > 1) FOLD(cpf1);
                if (nc > 2) FOLD(cpf2);
                if (nc > 3) FOLD(cpf3);
                const int2* cpp = corr_pack + (size_t)p1*MAXDEG;
                for (int c = 4; c < nc; ++c) FOLD(cpp[c]);
                if (nd == 0) {
                    float h0 = 0.f, h1 = 0.f;
                    if (cnt_s[p1] > 0) {
                        h0 = 1.0f/(1.0f + __expf(-m.x));
                        h1 = 1.0f/(1.0f + __expf(-m.y));
                    }
                    *(unsigned int*)&h_sb[side][ln*2] = pack2bf(h0, h1);
                } else {
                    mwork = m; dc0 = d0; dc1 = d1;
                }
                ndef = nd;
                if (ln == 0) defflag[side] = nd;
                const int pn = ((i+2 < BB) ? (i+2) : (BB-1))*2 + side;
                mnext = *(const float2*)&maxpre[(size_t)pn*DD + ln*2];
                const int2* cppn = corr_pack + (size_t)pn*MAXDEG;
                cpf0 = cppn[0]; cpf1 = cppn[1]; cpf2 = cppn[2]; cpf3 = cppn[3];
            } else if (wv <= 3) {
                const int r2 = wv - 2;
                const int s = zsrc_s[(i+1)*2 + r2];
                unsigned int zw;
                if (s & SRCF) {
                    const int row = s & 0xFFFF;
                    if ((row >> 1) == i) {
                        const float2 zv2 = *(const float2*)&zupd_s[row & 1][ln*2];
                        zw = pack2bf(zv2.x, zv2.y);
                    } else {
                        zw = *(const unsigned*)&zlog_sb[row*DD + ln*2];
                    }
                } else {
                    zw = pack2bf(zn2.x, zn2.y);
                }
                unsigned short* dst = (wv == 3) ? zvb : zub;
                *(unsigned int*)&dst[ln*2] = zw;
                const int i2 = (i+2 < BB) ? (i+2) : (BB-1);
                const int s2 = zsrc_s[i2*2 + r2];
                if (!(s2 & SRCF)) zn2 = *(const float2*)&z0[(size_t)s2*DD + ln*2];
            } else if (wv == 4) {
                const float* tdp = &tdi_s[(i+1)*8];
                tdw_s[0][ln*2]   = tdp[0]*wtA.x + tdp[1]*wtA.y + tdp[2]*wtA.z + tdp[3]*wtA.w;
                tdw_s[0][ln*2+1] = tdp[0]*wtB.x + tdp[1]*wtB.y + tdp[2]*wtB.z + tdp[3]*wtB.w;
                tdw_s[1][ln*2]   = tdp[4]*wtA.x + tdp[5]*wtA.y + tdp[6]*wtA.z + tdp[7]*wtA.w;
                tdw_s[1][ln*2+1] = tdp[4]*wtB.x + tdp[5]*wtB.y + tdp[6]*wtB.z + tdp[7]*wtB.w;
            }
        }
        LBAR();   // B3
    }

    // ---- batched zlog dump (only global store in the kernel) ----
    for (int e = t; e < BB*DD; e += 512) {        // BB*DD u32 chunks = 2*BB*DD bf16
        const unsigned pk = *(const unsigned*)&zlog_sb[e*2];
        float2 val;
        val.x = __uint_as_float(pk << 16);
        val.y = __uint_as_float(pk & 0xffff0000u);
        *(float2*)&zlog[(size_t)e*2] = val;
    }
}

// ---------------- intensity epilogue (parallel, reads via src indices) ----------------
__global__ void lam_kernel(const float* __restrict__ z0, const float* __restrict__ zlog,
                           const int* __restrict__ zsrc, const int* __restrict__ negsrc,
                           const int* __restrict__ et,
                           const float* __restrict__ w0, const float* __restrict__ b0,
                           const float* __restrict__ w1, const float* __restrict__ b1,
                           const float* __restrict__ psi,
                           float* __restrict__ out)
{
    const int b   = blockIdx.x;
    const int i   = b / 11;
    const int col = b % 11;
    const int l   = threadIdx.x;

    auto rp = [&](int s) -> const float* {
        return (s & SRCF) ? (zlog + (size_t)(s & 0xFFFF)*DD) : (z0 + (size_t)s*DD);
    };
    const float* xu;
    const float* xv;
    if (col == 0) { xu = rp(zsrc[i*2]); xv = rp(zsrc[i*2+1]); }
    else {
        const int k = col - 1;
        xu = (k < QQ) ? rp(zsrc[i*2])            : rp(negsrc[i*2*QQ + k]);
        xv = (k < QQ) ? rp(negsrc[i*2*QQ + k])   : rp(zsrc[i*2+1]);
    }
    float g0 = xu[l]*w0[l] + xu[l+64]*w0[l+64] + xv[l]*w0[DD+l] + xv[l+64]*w0[DD+l+64];
    float g1 = xu[l]*w1[l] + xu[l+64]*w1[l+64] + xv[l]*w1[DD+l] + xv[l+64]*w1[DD+l+64];
    #pragma unroll
    for (int s = 32; s >= 1; s >>= 1) { g0 += __shfl_xor(g0, s); g1 += __shfl_xor(g1, s); }
    if (l == 0) {
        g0 += b0[0]; g1 += b1[0];
        const float p0 = psi[0], p1 = psi[1];
        float r;
        if (col == 0) {
            const int e = et[i];
            const float g = e ? g1 : g0;
            const float p = e ? p1 : p0;
            const float y = g / (p + 1e-7f);
            r = p * (fmaxf(y, 0.f) + log1pf(expf(-fabsf(y))));
        } else {
            const float y0 = g0 / (p0 + 1e-7f);
            const float y1 = g1 / (p1 + 1e-7f);
            r = p0 * (fmaxf(y0, 0.f) + log1pf(expf(-fabsf(y0))))
              + p1 * (fmaxf(y1, 0.f) + log1pf(expf(-fabsf(y1))));
        }
        out[i*11 + col] = r;
    }
}

extern "C" void kernel_launch(void* const* d_in, const int* in_sizes, int n_in,
                              void* d_out, int out_size, void* d_ws, size_t ws_size,
                              hipStream_t stream)
{
    const int*   u   = (const int*)d_in[0];
    const int*   v   = (const int*)d_in[1];
    const int*   et  = (const int*)d_in[2];
    const float* td  = (const float*)d_in[3];
    const int*   neg = (const int*)d_in[4];
    const float* z0  = (const float*)d_in[5];
    const float* A   = (const float*)d_in[6];
    const float* S   = (const float*)d_in[7];
    const float* w0  = (const float*)d_in[8];
    const float* b0  = (const float*)d_in[9];
    const float* w1  = (const float*)d_in[10];
    const float* b1  = (const float*)d_in[11];
    const float* psi = (const float*)d_in[12];
    const float* Wh  = (const float*)d_in[13];
    const float* bh  = (const float*)d_in[14];
    const float* Wst = (const float*)d_in[15];
    const float* bst = (const float*)d_in[16];
    const float* Wrc = (const float*)d_in[17];
    const float* brc = (const float*)d_in[18];
    const float* Wt  = (const float*)d_in[19];
    const float* bt  = (const float*)d_in[20];

    char* ws = (char*)d_ws;
    size_t off = 0;
    auto alloc = [&](size_t bytes) {
        void* p = ws + off;
        off = (off + bytes + 255) & ~(size_t)255;
        return p;
    };
    float* Whz0   = (float*)alloc((size_t)NN*DD*sizeof(float));
    float* maxpre = (float*)alloc((size_t)2*BB*DD*sizeof(float));
    float* zlog   = (float*)alloc((size_t)2*BB*DD*sizeof(float));
    int*   ncnt   = (int*)alloc((size_t)2*BB*sizeof(int));
    int*   ncorr  = (int*)alloc((size_t)2*BB*sizeof(int));
    int2*  cpk    = (int2*)alloc((size_t)2*BB*MAXDEG*sizeof(int2));
    int*   zsrc   = (int*)alloc((size_t)2*BB*sizeof(int));
    int*   negsrc = (int*)alloc((size_t)BB*2*QQ*sizeof(int));
    int2*  npk    = (int2*)alloc((size_t)2*BB*MAXDEG*sizeof(int2));

    whz_init<<<NN/16, 512, 0, stream>>>(z0, Wh, bh, Whz0);
    nbr_kernel<<<2*BB, 256, 0, stream>>>(u, v, A, S, ncnt, npk);
    src_kernel<<<BB, 64, 0, stream>>>(u, v, neg, zsrc, negsrc);
    prep_kernel<<<2*BB, 128, 0, stream>>>(u, v, ncnt, npk, Whz0, maxpre, ncorr, cpk);
    scan_kernel<<<1, 512, 0, stream>>>(z0, td, ncnt, ncorr, cpk, maxpre, zsrc,
                                       Wh, bh, Wst, bst, Wrc, brc, Wt, bt, zlog);
    lam_kernel<<<BB*(1 + 2*QQ), 64, 0, stream>>>(z0, zlog, zsrc, negsrc, et,
                                                 w0, b0, w1, b1, psi, (float*)d_out);
}

// Round 15
// 214.133 us; speedup vs baseline: 1.2847x; 1.2178x over previous
//
#include <hip/hip_runtime.h>

#define NN 4096
#define DD 128
#define BB 128
#define QQ 5
#define MAXDEG 96
#define SRCF 0x40000000

typedef __attribute__((ext_vector_type(8))) short bf16x8;
typedef __attribute__((ext_vector_type(4))) float f32x4;

// LDS-only barrier: order ds ops, sync waves, never drain vmcnt.
#define LBAR() do { asm volatile("s_waitcnt lgkmcnt(0)" ::: "memory"); \
                    __builtin_amdgcn_sched_barrier(0); \
                    __builtin_amdgcn_s_barrier(); \
                    __builtin_amdgcn_sched_barrier(0); } while (0)

__device__ __forceinline__ float dot4f(float4 a, float4 b) {
    return a.x*b.x + a.y*b.y + a.z*b.z + a.w*b.w;
}
__device__ __forceinline__ unsigned short bfr(float x) {
    unsigned u = __float_as_uint(x);
    return (unsigned short)((u + 0x7fffu + ((u >> 16) & 1u)) >> 16);
}
__device__ __forceinline__ unsigned int pack2bf(float lo, float hi) {
    return ((unsigned int)bfr(hi) << 16) | (unsigned int)bfr(lo);
}

// ---------------- neighbor-list precompute (parallel) ----------------
__global__ void nbr_kernel(const int* __restrict__ u, const int* __restrict__ v,
                           const float* __restrict__ A, const float* __restrict__ S,
                           int* __restrict__ nbr_cnt, int2* __restrict__ nbr_pack)
{
    __shared__ int   lcnt[257];
    __shared__ int   sidx[MAXDEG];
    __shared__ float sq[MAXDEG];
    __shared__ float ssum;
    __shared__ int   stot;

    const int p    = blockIdx.x;
    const int i    = p >> 1;
    const int side = p & 1;
    const int other = (side == 0) ? v[i] : u[i];
    const float* Arow = A + (size_t)other * NN;
    const float* Srow = S + (size_t)other * NN;
    const int tid = threadIdx.x;

    const int base = tid * 16;
    int c0 = 0;
    for (int j = 0; j < 16; ++j) c0 += (Arow[base + j] > 0.0f) ? 1 : 0;
    lcnt[tid] = c0;
    __syncthreads();
    if (tid == 0) {
        int s = 0;
        for (int k = 0; k < 256; ++k) { int c = lcnt[k]; lcnt[k] = s; s += c; }
        stot = s;
    }
    __syncthreads();
    int off = lcnt[tid];
    for (int j = 0; j < 16; ++j) {
        if (Arow[base + j] > 0.0f) {
            if (off < MAXDEG) sidx[off] = base + j;
            ++off;
        }
    }
    __syncthreads();
    int cnt = stot; if (cnt > MAXDEG) cnt = MAXDEG;
    for (int jj = tid; jj < cnt; jj += 256) sq[jj] = expf(Srow[sidx[jj]]);
    __syncthreads();
    if (tid == 0) {
        float s = 0.0f;
        for (int jj = 0; jj < cnt; ++jj) s += sq[jj];
        ssum = s + 1e-7f;
    }
    __syncthreads();
    for (int jj = tid; jj < cnt; jj += 256) {
        int2 pk;
        pk.x = sidx[jj];
        pk.y = __float_as_int(sq[jj] / ssum);
        nbr_pack[p * MAXDEG + jj] = pk;
    }
    if (tid == 0) nbr_cnt[p] = cnt;
}

// ---------------- Whz0[n][d] = z0[n].Wh[d] + bh[d] ----------------
__global__ __launch_bounds__(512) void whz_init(
    const float* __restrict__ z0, const float* __restrict__ Wh, const float* __restrict__ bh,
    float* __restrict__ Whz0)
{
    const int t   = threadIdx.x;
    const int rep = t & 7;
    const int d0  = t >> 3;
    float4 wh0[4], wh1[4];
    #pragma unroll
    for (int m = 0; m < 4; ++m) {
        wh0[m] = *(const float4*)(Wh + (size_t)d0*DD + rep*16 + m*4);
        wh1[m] = *(const float4*)(Wh + (size_t)(d0+64)*DD + rep*16 + m*4);
    }
    const float bh0 = bh[d0], bh1 = bh[d0+64];
    const int r0 = blockIdx.x * 16;
    for (int r = r0; r < r0 + 16; ++r) {
        const float* zr = z0 + (size_t)r*DD + rep*16;
        float a0 = 0.f, a1 = 0.f;
        #pragma unroll
        for (int m = 0; m < 4; ++m) {
            float4 zz = *(const float4*)(zr + m*4);
            a0 += dot4f(zz, wh0[m]);
            a1 += dot4f(zz, wh1[m]);
        }
        a0 += __shfl_xor(a0,1); a0 += __shfl_xor(a0,2); a0 += __shfl_xor(a0,4);
        a1 += __shfl_xor(a1,1); a1 += __shfl_xor(a1,2); a1 += __shfl_xor(a1,4);
        if (rep == 0) {
            Whz0[(size_t)r*DD + d0]    = a0 + bh0;
            Whz0[(size_t)r*DD + d0+64] = a1 + bh1;
        }
    }
}

// ---------------- last-update sources for u,v,neg rows ----------------
__global__ void src_kernel(const int* __restrict__ u, const int* __restrict__ v,
                           const int* __restrict__ neg,
                           int* __restrict__ zsrc, int* __restrict__ negsrc)
{
    const int i = blockIdx.x;
    const int k = threadIdx.x;
    if (k >= 2 + 2*QQ) return;
    const int n = (k == 0) ? u[i] : (k == 1) ? v[i] : neg[i*2*QQ + (k-2)];
    int s = n;
    for (int j = i-1; j >= 0; --j) {
        if (v[j] == n) { s = SRCF | (j*2 + 1); break; }
        if (u[j] == n) { s = SRCF | (j*2 + 0); break; }
    }
    if (k < 2) zsrc[i*2 + k] = s;
    else       negsrc[i*2*QQ + (k-2)] = s;
}

// ---------------- static-max + correction lists per (i,side) ----------------
__global__ void prep_kernel(const int* __restrict__ u, const int* __restrict__ v,
                            const int* __restrict__ nbr_cnt, const int2* __restrict__ nbr_pack,
                            const float* __restrict__ Whz0,
                            float* __restrict__ maxpre, int* __restrict__ ncorr,
                            int2* __restrict__ corr_pack)
{
    __shared__ int   su[BB], sv[BB];
    __shared__ int   sidx[MAXDEG];
    __shared__ float sq[MAXDEG];
    __shared__ unsigned char cflag[MAXDEG];
    __shared__ int ccnt;

    const int p   = blockIdx.x;
    const int i   = p >> 1;
    const int tid = threadIdx.x;
    if (tid < BB) { su[tid] = u[tid]; sv[tid] = v[tid]; }
    if (tid == 0) ccnt = 0;
    const int cnt = nbr_cnt[p];
    for (int jj = tid; jj < cnt; jj += 128) {
        int2 pk = nbr_pack[p*MAXDEG + jj];
        sidx[jj] = pk.x; sq[jj] = __int_as_float(pk.y);
    }
    __syncthreads();
    for (int jj = tid; jj < cnt; jj += 128) {
        const int r = sidx[jj];
        int fs = -1;
        for (int j = i-1; j >= 0; --j) {
            if (sv[j] == r) { fs = j*2 + 1; break; }
            if (su[j] == r) { fs = j*2 + 0; break; }
        }
        if (fs >= 0) {
            const int pos = atomicAdd(&ccnt, 1);   // order-free (commutative max fold)
            int2 cp; cp.x = fs; cp.y = __float_as_int(sq[jj]);
            corr_pack[p*MAXDEG + pos] = cp;
            cflag[jj] = 1;
        } else cflag[jj] = 0;
    }
    __syncthreads();
    const int d = tid;
    float m = -3.0e38f;
    for (int jj = 0; jj < cnt; ++jj)
        if (!cflag[jj]) m = fmaxf(m, sq[jj] * Whz0[(size_t)sidx[jj]*DD + d]);
    maxpre[(size_t)p*DD + d] = m;
    if (tid == 0) ncorr[p] = ccnt;
}

// ---------------- pair dependency flags: does step 2g+1 depend on step 2g? ----------------
__global__ void pair_kernel(const int* __restrict__ zsrc, const int* __restrict__ ncorr,
                            const int2* __restrict__ corr_pack, int* __restrict__ pdep)
{
    const int g = blockIdx.x;            // 0..63
    const int tid = threadIdx.x;         // 0..63
    const int Astep = 2*g, Bstep = 2*g+1;
    __shared__ int dep;
    if (tid == 0) dep = 0;
    __syncthreads();
    if (tid < 2) {
        const int s = zsrc[Bstep*2 + tid];
        if ((s & SRCF) && (((s & 0xFFFF) >> 1) == Astep)) atomicOr(&dep, 1);
    }
    for (int k = 0; k < 2; ++k) {
        const int p = Bstep*2 + k;
        const int nc = ncorr[p];
        for (int c = tid; c < nc; c += 64)
            if ((corr_pack[p*MAXDEG + c].x >> 1) == Astep) atomicOr(&dep, 1);
    }
    __syncthreads();
    if (tid == 0) pdep[g] = dep;
}

// ---------------- sequential scan: 64 PAIRED groups, 2 phases/group fast path ----------------
// Pair G = steps A=2G, B=2G+1. z_upd GEMM does 4 cols (u(A),v(A),u(B),v(B)); whz GEMM 4 rows.
// pdep[G]=1 (rare): 6-phase slow path. Deferred cross-pair corrections (<=4/side) fold at
// next group's FIXUP; intra-pair (<=2/side) fold in the slow path's mini phase.
__global__ __launch_bounds__(512) void scan_kernel(
    const float* __restrict__ z0, const float* __restrict__ time_diff,
    const int* __restrict__ nbr_cnt, const int* __restrict__ ncorr,
    const int2* __restrict__ corr_pack,
    const float* __restrict__ maxpre, const int* __restrict__ zsrc,
    const int* __restrict__ pdep,
    const float* __restrict__ Wh,  const float* __restrict__ bh,
    const float* __restrict__ Wst, const float* __restrict__ bst,
    const float* __restrict__ Wrc, const float* __restrict__ brc,
    const float* __restrict__ Wt,  const float* __restrict__ bt,
    float* __restrict__ zlog)
{
    __shared__ __align__(16) unsigned short whz_sb[2*BB*DD];   // 64 KB whz log (bf16)
    __shared__ __align__(16) unsigned short zlog_sb[2*BB*DD];  // 64 KB z log (bf16)
    __shared__ __align__(16) unsigned short h_b[4][DD];        // h operands (4 cols)
    __shared__ __align__(16) unsigned short zrow_b[4][DD];     // z operands (4 cols)
    __shared__ __align__(16) float zupd_s[4][DD];
    __shared__ __align__(16) unsigned short zupdb[4][DD];
    __shared__ __align__(16) float tdw_s[4][DD];
    __shared__ __align__(16) float tdi_s[BB*8];
    __shared__ int cnt_s[2*BB], ncorr_s[2*BB], zsrc_s[2*BB];
    __shared__ int pdep_s[BB/2];
    __shared__ int defflag[4];

    const int t    = threadIdx.x;
    const int wv   = t >> 6;
    const int ln   = t & 63;
    const int arow = wv*16 + (ln & 15);
    const int kgrp = ln >> 4;
    const int ncol = ln & 15;
    const int dbase = wv*16 + kgrp*4;

    // ---- persistent A-fragments (packed bf16 -> remat-proof) ----
    bf16x8 afw[8];   // [Wst | Wrc], K=256
    #pragma unroll
    for (int kt = 0; kt < 8; ++kt) {
        const int kb = kt*32 + kgrp*8;
        const float* src = (kb < 128) ? (Wst + (size_t)arow*DD + kb)
                                      : (Wrc + (size_t)arow*DD + (kb - 128));
        #pragma unroll
        for (int j = 0; j < 8; ++j) afw[kt][j] = (short)bfr(src[j]);
    }
    bf16x8 afh[4];   // Wh, K=128
    #pragma unroll
    for (int kt = 0; kt < 4; ++kt) {
        const float* src = Wh + (size_t)arow*DD + kt*32 + kgrp*8;
        #pragma unroll
        for (int j = 0; j < 8; ++j) afh[kt][j] = (short)bfr(src[j]);
    }
    f32x4 bsv, bhv;
    #pragma unroll
    for (int r = 0; r < 4; ++r) {
        bsv[r] = bst[dbase+r] + brc[dbase+r] + bt[dbase+r];
        bhv[r] = bh[dbase+r];
    }
    const float4 wtA = *(const float4*)(Wt + (size_t)(ln*2)*4);
    const float4 wtB = *(const float4*)(Wt + (size_t)(ln*2+1)*4);

    // ---- one-time LDS preloads ----
    if (t < 256)      { cnt_s[t] = nbr_cnt[t]; ncorr_s[t] = ncorr[t]; }
    else              { zsrc_s[t-256] = zsrc[t-256]; }
    if (t < BB/2)     pdep_s[t] = pdep[t];
    if (t < 4)        defflag[t] = 0;
    {
        const float sdv[4] = {50.f, 7.f, 15.f, 15.f};
        for (int e = t; e < BB*8; e += 512) tdi_s[e] = time_diff[e] / sdv[e & 3];
    }
    __syncthreads();

    // ---- wave-private pipeline state ----
    float2 mwork = make_float2(0.f, 0.f);
    float2 mnext = make_float2(0.f, 0.f);
    int2 cpf0, cpf1, cpf2, cpf3;
    int2 de0, de1, de2, de3; int ndefr = 0;
    int2 ie0, ie1;           int nintra = 0;
    float2 zn2 = make_float2(0.f, 0.f);

    // ================= helper lambdas =================
    auto DO_P1 = [&]() {
        const int cc = (ncol < 4) ? ncol : 0;
        const unsigned short* hp = &h_b[cc][0];
        const unsigned short* zp = &zrow_b[cc][0];
        f32x4 accA = {0.f,0.f,0.f,0.f}, accB = {0.f,0.f,0.f,0.f};
        #pragma unroll
        for (int kt = 0; kt < 4; kt += 2) {
            bf16x8 b0 = *(const bf16x8*)&hp[kt*32 + kgrp*8];
            bf16x8 b1 = *(const bf16x8*)&hp[(kt+1)*32 + kgrp*8];
            accA = __builtin_amdgcn_mfma_f32_16x16x32_bf16(afw[kt],   b0, accA, 0,0,0);
            accB = __builtin_amdgcn_mfma_f32_16x16x32_bf16(afw[kt+1], b1, accB, 0,0,0);
        }
        #pragma unroll
        for (int kt = 4; kt < 8; kt += 2) {
            bf16x8 b0 = *(const bf16x8*)&zp[(kt-4)*32 + kgrp*8];
            bf16x8 b1 = *(const bf16x8*)&zp[(kt-3)*32 + kgrp*8];
            accA = __builtin_amdgcn_mfma_f32_16x16x32_bf16(afw[kt],   b0, accA, 0,0,0);
            accB = __builtin_amdgcn_mfma_f32_16x16x32_bf16(afw[kt+1], b1, accB, 0,0,0);
        }
        if (ncol < 4) {
            const f32x4 tdwv = *(const f32x4*)&tdw_s[ncol][dbase];
            f32x4 zu4;
            #pragma unroll
            for (int r = 0; r < 4; ++r) {
                const float a = accA[r] + accB[r] + bsv[r] + tdwv[r];
                zu4[r] = 1.0f/(1.0f + __expf(-a));
            }
            *(f32x4*)&zupd_s[ncol][dbase] = zu4;
            uint2 pk;
            pk.x = pack2bf(zu4[0], zu4[1]);
            pk.y = pack2bf(zu4[2], zu4[3]);
            *(uint2*)&zupdb[ncol][dbase] = pk;
        }
    };

    auto DO_P2 = [&](int writeAll, int G) {
        const int cc = (ncol < 4) ? ncol : 0;
        const unsigned short* up = &zupdb[cc][0];
        f32x4 accA = {0.f,0.f,0.f,0.f}, accB = {0.f,0.f,0.f,0.f};
        {
            bf16x8 b0 = *(const bf16x8*)&up[0*32 + kgrp*8];
            bf16x8 b1 = *(const bf16x8*)&up[1*32 + kgrp*8];
            bf16x8 b2 = *(const bf16x8*)&up[2*32 + kgrp*8];
            bf16x8 b3 = *(const bf16x8*)&up[3*32 + kgrp*8];
            accA = __builtin_amdgcn_mfma_f32_16x16x32_bf16(afh[0], b0, accA, 0,0,0);
            accB = __builtin_amdgcn_mfma_f32_16x16x32_bf16(afh[1], b1, accB, 0,0,0);
            accA = __builtin_amdgcn_mfma_f32_16x16x32_bf16(afh[2], b2, accA, 0,0,0);
            accB = __builtin_amdgcn_mfma_f32_16x16x32_bf16(afh[3], b3, accB, 0,0,0);
        }
        if (ncol < 4 && (writeAll || ncol < 2)) {
            const int row = 4*G + ncol;
            uint2 wpk;
            wpk.x = pack2bf(accA[0]+accB[0]+bhv[0], accA[1]+accB[1]+bhv[1]);
            wpk.y = pack2bf(accA[2]+accB[2]+bhv[2], accA[3]+accB[3]+bhv[3]);
            *(uint2*)&whz_sb[row*DD + dbase] = wpk;
            const f32x4 zu4 = *(const f32x4*)&zupd_s[ncol][dbase];
            uint2 zpk;
            zpk.x = pack2bf(zu4[0], zu4[1]);
            zpk.y = pack2bf(zu4[2], zu4[3]);
            *(uint2*)&zlog_sb[row*DD + dbase] = zpk;
        }
    };

    // Prepare pair curG+1 = steps {C, C+1}; classify corrections; publish what's ready.
    auto PREP = [&](int curG) {
        const int C = 2*curG + 2;
        if (C >= BB) return;
        if (wv < 4) {
            const int step = C + (wv >> 1);
            const int side = wv & 1;
            const int p1 = step*2 + side;
            const int nc = ncorr_s[p1];
            float2 m = mnext;
            int nd = 0, ni = 0;
            int2 dl0, dl1, dl2, dl3, il0, il1;
            auto FOLD = [&](int2 e) {
                if ((e.x >> 2) == curG) {                       // src in current pair -> defer
                    if (nd==0) dl0=e; else if (nd==1) dl1=e; else if (nd==2) dl2=e; else dl3=e;
                    ++nd;
                } else if ((e.x >> 1) == C && step == C+1) {    // intra-next-pair (h of D only)
                    if (ni==0) il0=e; else il1=e;
                    ++ni;
                } else {
                    const float qc = __int_as_float(e.y);
                    const unsigned pk = *(const unsigned*)&whz_sb[e.x*DD + ln*2];
                    m.x = fmaxf(m.x, qc * __uint_as_float(pk << 16));
                    m.y = fmaxf(m.y, qc * __uint_as_float(pk & 0xffff0000u));
                }
            };
            if (nc > 0) FOLD(cpf0);
            if (nc > 1) FOLD(cpf1);
            if (nc > 2) FOLD(cpf2);
            if (nc > 3) FOLD(cpf3);
            const int2* cpp = corr_pack + (size_t)p1*MAXDEG;
            for (int c = 4; c < nc; ++c) FOLD(cpp[c]);
            mwork = m; ndefr = nd; nintra = ni;
            de0=dl0; de1=dl1; de2=dl2; de3=dl3; ie0=il0; ie1=il1;
            if (nd == 0 && ni == 0) {
                float h0 = 0.f, h1 = 0.f;
                if (cnt_s[p1] > 0) {
                    h0 = 1.0f/(1.0f + __expf(-m.x));
                    h1 = 1.0f/(1.0f + __expf(-m.y));
                }
                *(unsigned*)&h_b[wv][ln*2] = pack2bf(h0, h1);
            }
            if (ln == 0) defflag[wv] = nd;
            const int Cn = C + 2;
            const int stepn = (Cn + (wv>>1) < BB) ? (Cn + (wv>>1)) : step;
            const int pn = stepn*2 + side;
            mnext = *(const float2*)&maxpre[(size_t)pn*DD + ln*2];
            const int2* cppn = corr_pack + (size_t)pn*MAXDEG;
            cpf0 = cppn[0]; cpf1 = cppn[1]; cpf2 = cppn[2]; cpf3 = cppn[3];
        } else {
            const int k = wv - 4;
            const int step = C + (k >> 1);
            const int uvk = k & 1;
            const int s = zsrc_s[step*2 + uvk];
            if (s & SRCF) {
                const int row = s & 0xFFFF;
                const int rg  = row >> 2;
                if (rg == curG) {
                    const float2 zf = *(const float2*)&zupd_s[row & 3][ln*2];
                    *(unsigned*)&zrow_b[k][ln*2] = pack2bf(zf.x, zf.y);
                } else if (rg < curG || curG < 0 ? (rg < curG) : false) {
                    // unreachable placeholder (handled below)
                } else if (rg < curG) {
                    *(unsigned*)&zrow_b[k][ln*2] = *(const unsigned*)&zlog_sb[row*DD + ln*2];
                }
                if (rg < curG) {
                    *(unsigned*)&zrow_b[k][ln*2] = *(const unsigned*)&zlog_sb[row*DD + ln*2];
                }
                // rg == curG+1 (B references A of the NEXT pair): slow path republishes
            } else {
                *(unsigned*)&zrow_b[k][ln*2] = pack2bf(zn2.x, zn2.y);
            }
            if (wv == 4) {
                const float* tp = &tdi_s[C*8];
                tdw_s[0][ln*2]   = tp[0]*wtA.x + tp[1]*wtA.y + tp[2]*wtA.z + tp[3]*wtA.w;
                tdw_s[0][ln*2+1] = tp[0]*wtB.x + tp[1]*wtB.y + tp[2]*wtB.z + tp[3]*wtB.w;
                tdw_s[1][ln*2]   = tp[4]*wtA.x + tp[5]*wtA.y + tp[6]*wtA.z + tp[7]*wtA.w;
                tdw_s[1][ln*2+1] = tp[4]*wtB.x + tp[5]*wtB.y + tp[6]*wtB.z + tp[7]*wtB.w;
            } else if (wv == 5) {
                const float* tp = &tdi_s[(C+1)*8];
                tdw_s[2][ln*2]   = tp[0]*wtA.x + tp[1]*wtA.y + tp[2]*wtA.z + tp[3]*wtA.w;
                tdw_s[2][ln*2+1] = tp[0]*wtB.x + tp[1]*wtB.y + tp[2]*wtB.z + tp[3]*wtB.w;
                tdw_s[3][ln*2]   = tp[4]*wtA.x + tp[5]*wtA.y + tp[6]*wtA.z + tp[7]*wtA.w;
                tdw_s[3][ln*2+1] = tp[4]*wtB.x + tp[5]*wtB.y + tp[6]*wtB.z + tp[7]*wtB.w;
            }
            const int Cn = C + 2;
            if (Cn + (k>>1) < BB) {
                const int sn = zsrc_s[(Cn + (k>>1))*2 + uvk];
                if (!(sn & SRCF)) zn2 = *(const float2*)&z0[(size_t)sn*DD + ln*2];
            }
        }
    };

    // ---- priming: prefetch + prepare pair 0 ----
    if (wv < 4) {
        const int p0 = (wv >> 1)*2 + (wv & 1);
        mnext = *(const float2*)&maxpre[(size_t)p0*DD + ln*2];
        const int2* cpp = corr_pack + (size_t)p0*MAXDEG;
        cpf0 = cpp[0]; cpf1 = cpp[1]; cpf2 = cpp[2]; cpf3 = cpp[3];
    } else {
        const int k = wv - 4;
        const int s = zsrc_s[(k >> 1)*2 + (k & 1)];
        if (!(s & SRCF)) zn2 = *(const float2*)&z0[(size_t)s*DD + ln*2];
    }
    PREP(-1);
    LBAR();

    // ================= main loop over 64 pairs =================
    for (int G = 0; G < BB/2; ++G) {
        // ---- FIXUP: fold deferred cross-pair corrections (whz of pair G-1 now final) ----
        if (defflag[0] | defflag[1] | defflag[2] | defflag[3]) {
            if (wv < 4 && ndefr) {
                float2 m = mwork;
                {
                    const float qc = __int_as_float(de0.y);
                    const unsigned pk = *(const unsigned*)&whz_sb[de0.x*DD + ln*2];
                    m.x = fmaxf(m.x, qc * __uint_as_float(pk << 16));
                    m.y = fmaxf(m.y, qc * __uint_as_float(pk & 0xffff0000u));
                }
                if (ndefr > 1) {
                    const float qc = __int_as_float(de1.y);
                    const unsigned pk = *(const unsigned*)&whz_sb[de1.x*DD + ln*2];
                    m.x = fmaxf(m.x, qc * __uint_as_float(pk << 16));
                    m.y = fmaxf(m.y, qc * __uint_as_float(pk & 0xffff0000u));
                }
                if (ndefr > 2) {
                    const float qc = __int_as_float(de2.y);
                    const unsigned pk = *(const unsigned*)&whz_sb[de2.x*DD + ln*2];
                    m.x = fmaxf(m.x, qc * __uint_as_float(pk << 16));
                    m.y = fmaxf(m.y, qc * __uint_as_float(pk & 0xffff0000u));
                }
                if (ndefr > 3) {
                    const float qc = __int_as_float(de3.y);
                    const unsigned pk = *(const unsigned*)&whz_sb[de3.x*DD + ln*2];
                    m.x = fmaxf(m.x, qc * __uint_as_float(pk << 16));
                    m.y = fmaxf(m.y, qc * __uint_as_float(pk & 0xffff0000u));
                }
                mwork = m; ndefr = 0;
                if (nintra == 0) {
                    const int p1 = (2*G + (wv>>1))*2 + (wv & 1);
                    float h0 = 0.f, h1 = 0.f;
                    if (cnt_s[p1] > 0) {
                        h0 = 1.0f/(1.0f + __expf(-m.x));
                        h1 = 1.0f/(1.0f + __expf(-m.y));
                    }
                    *(unsigned*)&h_b[wv][ln*2] = pack2bf(h0, h1);
                }
            }
            LBAR();
        }

        if (!pdep_s[G]) {
            // -------- fast path: 2 phases for 2 steps --------
            DO_P1();
            LBAR();
            DO_P2(1, G);
            PREP(G);
            LBAR();
        } else {
            // -------- slow path: step A then step B --------
            DO_P1();                         // cols 2,3 provisional garbage (finite)
            LBAR();
            DO_P2(0, G);                     // whz rows 4G, 4G+1 only
            if (wv >= 6) {                   // republish z rows of B that reference A
                const int k = wv - 4;        // 2,3
                const int s = zsrc_s[(2*G+1)*2 + (k & 1)];
                if ((s & SRCF) && (((s & 0xFFFF) >> 2) == G)) {
                    const int row = s & 0xFFFF;
                    const float2 zf = *(const float2*)&zupd_s[row & 3][ln*2];
                    *(unsigned*)&zrow_b[k][ln*2] = pack2bf(zf.x, zf.y);
                }
            }
            LBAR();
            // mini: fold intra-pair corrections into h of B
            if ((wv == 2 || wv == 3) && nintra) {
                float2 m = mwork;
                {
                    const float qc = __int_as_float(ie0.y);
                    const unsigned pk = *(const unsigned*)&whz_sb[ie0.x*DD + ln*2];
                    m.x = fmaxf(m.x, qc * __uint_as_float(pk << 16));
                    m.y = fmaxf(m.y, qc * __uint_as_float(pk & 0xffff0000u));
                }
                if (nintra > 1) {
                    const float qc = __int_as_float(ie1.y);
                    const unsigned pk = *(const unsigned*)&whz_sb[ie1.x*DD + ln*2];
                    m.x = fmaxf(m.x, qc * __uint_as_float(pk << 16));
                    m.y = fmaxf(m.y, qc * __uint_as_float(pk & 0xffff0000u));
                }
                const int p1 = (2*G+1)*2 + (wv & 1);
                float h0 = 0.f, h1 = 0.f;
                if (cnt_s[p1] > 0) {
                    h0 = 1.0f/(1.0f + __expf(-m.x));
                    h1 = 1.0f/(1.0f + __expf(-m.y));
                }
                *(unsigned*)&h_b[wv][ln*2] = pack2bf(h0, h1);
                nintra = 0;
            }
            LBAR();
            DO_P1();                         // cols 2,3 now valid (0,1 recompute same)
            LBAR();
            DO_P2(1, G);
            PREP(G);
            LBAR();
        }
    }

    // ---- batched zlog dump (only global store in the kernel) ----
    for (int e = t; e < BB*DD; e += 512) {
        const unsigned pk = *(const unsigned*)&zlog_sb[e*2];
        float2 val;
        val.x = __uint_as_float(pk << 16);
        val.y = __uint_as_float(pk & 0xffff0000u);
        *(float2*)&zlog[(size_t)e*2] = val;
    }
}

// ---------------- intensity epilogue (parallel, reads via src indices) ----------------
__global__ void lam_kernel(const float* __restrict__ z0, const float* __restrict__ zlog,
                           const int* __restrict__ zsrc, const int* __restrict__ negsrc,
                           const int* __restrict__ et,
                           const float* __restrict__ w0, const float* __restrict__ b0,
                           const float* __restrict__ w1, const float* __restrict__ b1,
                           const float* __restrict__ psi,
                           float* __restrict__ out)
{
    const int b   = blockIdx.x;
    const int i   = b / 11;
    const int col = b % 11;
    const int l   = threadIdx.x;

    auto rp = [&](int s) -> const float* {
        return (s & SRCF) ? (zlog + (size_t)(s & 0xFFFF)*DD) : (z0 + (size_t)s*DD);
    };
    const float* xu;
    const float* xv;
    if (col == 0) { xu = rp(zsrc[i*2]); xv = rp(zsrc[i*2+1]); }
    else {
        const int k = col - 1;
        xu = (k < QQ) ? rp(zsrc[i*2])            : rp(negsrc[i*2*QQ + k]);
        xv = (k < QQ) ? rp(negsrc[i*2*QQ + k])   : rp(zsrc[i*2+1]);
    }
    float g0 = xu[l]*w0[l] + xu[l+64]*w0[l+64] + xv[l]*w0[DD+l] + xv[l+64]*w0[DD+l+64];
    float g1 = xu[l]*w1[l] + xu[l+64]*w1[l+64] + xv[l]*w1[DD+l] + xv[l+64]*w1[DD+l+64];
    #pragma unroll
    for (int s = 32; s >= 1; s >>= 1) { g0 += __shfl_xor(g0, s); g1 += __shfl_xor(g1, s); }
    if (l == 0) {
        g0 += b0[0]; g1 += b1[0];
        const float p0 = psi[0], p1 = psi[1];
        float r;
        if (col == 0) {
            const int e = et[i];
            const float g = e ? g1 : g0;
            const float p = e ? p1 : p0;
            const float y = g / (p + 1e-7f);
            r = p * (fmaxf(y, 0.f) + log1pf(expf(-fabsf(y))));
        } else {
            const float y0 = g0 / (p0 + 1e-7f);
            const float y1 = g1 / (p1 + 1e-7f);
            r = p0 * (fmaxf(y0, 0.f) + log1pf(expf(-fabsf(y0))))
              + p1 * (fmaxf(y1, 0.f) + log1pf(expf(-fabsf(y1))));
        }
        out[i*11 + col] = r;
    }
}

extern "C" void kernel_launch(void* const* d_in, const int* in_sizes, int n_in,
                              void* d_out, int out_size, void* d_ws, size_t ws_size,
                              hipStream_t stream)
{
    const int*   u   = (const int*)d_in[0];
    const int*   v   = (const int*)d_in[1];
    const int*   et  = (const int*)d_in[2];
    const float* td  = (const float*)d_in[3];
    const int*   neg = (const int*)d_in[4];
    const float* z0  = (const float*)d_in[5];
    const float* A   = (const float*)d_in[6];
    const float* S   = (const float*)d_in[7];
    const float* w0  = (const float*)d_in[8];
    const float* b0  = (const float*)d_in[9];
    const float* w1  = (const float*)d_in[10];
    const float* b1  = (const float*)d_in[11];
    const float* psi = (const float*)d_in[12];
    const float* Wh  = (const float*)d_in[13];
    const float* bh  = (const float*)d_in[14];
    const float* Wst = (const float*)d_in[15];
    const float* bst = (const float*)d_in[16];
    const float* Wrc = (const float*)d_in[17];
    const float* brc = (const float*)d_in[18];
    const float* Wt  = (const float*)d_in[19];
    const float* bt  = (const float*)d_in[20];

    char* ws = (char*)d_ws;
    size_t off = 0;
    auto alloc = [&](size_t bytes) {
        void* p = ws + off;
        off = (off + bytes + 255) & ~(size_t)255;
        return p;
    };
    float* Whz0   = (float*)alloc((size_t)NN*DD*sizeof(float));
    float* maxpre = (float*)alloc((size_t)2*BB*DD*sizeof(float));
    float* zlog   = (float*)alloc((size_t)2*BB*DD*sizeof(float));
    int*   ncnt   = (int*)alloc((size_t)2*BB*sizeof(int));
    int*   ncorr  = (int*)alloc((size_t)2*BB*sizeof(int));
    int2*  cpk    = (int2*)alloc((size_t)2*BB*MAXDEG*sizeof(int2));
    int*   zsrc   = (int*)alloc((size_t)2*BB*sizeof(int));
    int*   negsrc = (int*)alloc((size_t)BB*2*QQ*sizeof(int));
    int*   pdep   = (int*)alloc((size_t)(BB/2)*sizeof(int));
    int2*  npk    = (int2*)alloc((size_t)2*BB*MAXDEG*sizeof(int2));

    whz_init<<<NN/16, 512, 0, stream>>>(z0, Wh, bh, Whz0);
    nbr_kernel<<<2*BB, 256, 0, stream>>>(u, v, A, S, ncnt, npk);
    src_kernel<<<BB, 64, 0, stream>>>(u, v, neg, zsrc, negsrc);
    prep_kernel<<<2*BB, 128, 0, stream>>>(u, v, ncnt, npk, Whz0, maxpre, ncorr, cpk);
    pair_kernel<<<BB/2, 64, 0, stream>>>(zsrc, ncorr, cpk, pdep);
    scan_kernel<<<1, 512, 0, stream>>>(z0, td, ncnt, ncorr, cpk, maxpre, zsrc, pdep,
                                       Wh, bh, Wst, bst, Wrc, brc, Wt, bt, zlog);
    lam_kernel<<<BB*(1 + 2*QQ), 64, 0, stream>>>(z0, zlog, zsrc, negsrc, et,
                                                 w0, b0, w1, b1, psi, (float*)d_out);
}

// Round 16
// 194.404 us; speedup vs baseline: 1.4151x; 1.1015x over previous
//
#include <hip/hip_runtime.h>

#define NN 4096
#define DD 128
#define BB 128
#define QQ 5
#define MAXDEG 96
#define SRCF 0x40000000
#define HP 136   // ushort pitch for bf16 operand buffers: 272B rows -> +4 banks/row
#define FP 132   // float pitch for f32 operand buffers: 528B rows -> +4 banks/row

typedef __attribute__((ext_vector_type(8))) short bf16x8;
typedef __attribute__((ext_vector_type(4))) float f32x4;

// LDS-only barrier: order ds ops, sync waves, never drain vmcnt.
#define LBAR() do { asm volatile("s_waitcnt lgkmcnt(0)" ::: "memory"); \
                    __builtin_amdgcn_sched_barrier(0); \
                    __builtin_amdgcn_s_barrier(); \
                    __builtin_amdgcn_sched_barrier(0); } while (0)

__device__ __forceinline__ float dot4f(float4 a, float4 b) {
    return a.x*b.x + a.y*b.y + a.z*b.z + a.w*b.w;
}
__device__ __forceinline__ unsigned short bfr(float x) {
    unsigned u = __float_as_uint(x);
    return (unsigned short)((u + 0x7fffu + ((u >> 16) & 1u)) >> 16);
}
__device__ __forceinline__ unsigned int pack2bf(float lo, float hi) {
    return ((unsigned int)bfr(hi) << 16) | (unsigned int)bfr(lo);
}

// ---------------- neighbor-list precompute (parallel) ----------------
__global__ void nbr_kernel(const int* __restrict__ u, const int* __restrict__ v,
                           const float* __restrict__ A, const float* __restrict__ S,
                           int* __restrict__ nbr_cnt, int2* __restrict__ nbr_pack)
{
    __shared__ int   lcnt[257];
    __shared__ int   sidx[MAXDEG];
    __shared__ float sq[MAXDEG];
    __shared__ float ssum;
    __shared__ int   stot;

    const int p    = blockIdx.x;
    const int i    = p >> 1;
    const int side = p & 1;
    const int other = (side == 0) ? v[i] : u[i];
    const float* Arow = A + (size_t)other * NN;
    const float* Srow = S + (size_t)other * NN;
    const int tid = threadIdx.x;

    const int base = tid * 16;
    int c0 = 0;
    for (int j = 0; j < 16; ++j) c0 += (Arow[base + j] > 0.0f) ? 1 : 0;
    lcnt[tid] = c0;
    __syncthreads();
    if (tid == 0) {
        int s = 0;
        for (int k = 0; k < 256; ++k) { int c = lcnt[k]; lcnt[k] = s; s += c; }
        stot = s;
    }
    __syncthreads();
    int off = lcnt[tid];
    for (int j = 0; j < 16; ++j) {
        if (Arow[base + j] > 0.0f) {
            if (off < MAXDEG) sidx[off] = base + j;
            ++off;
        }
    }
    __syncthreads();
    int cnt = stot; if (cnt > MAXDEG) cnt = MAXDEG;
    for (int jj = tid; jj < cnt; jj += 256) sq[jj] = expf(Srow[sidx[jj]]);
    __syncthreads();
    if (tid == 0) {
        float s = 0.0f;
        for (int jj = 0; jj < cnt; ++jj) s += sq[jj];
        ssum = s + 1e-7f;
    }
    __syncthreads();
    for (int jj = tid; jj < cnt; jj += 256) {
        int2 pk;
        pk.x = sidx[jj];
        pk.y = __float_as_int(sq[jj] / ssum);
        nbr_pack[p * MAXDEG + jj] = pk;
    }
    if (tid == 0) nbr_cnt[p] = cnt;
}

// ---------------- Whz0[n][d] = z0[n].Wh[d] + bh[d] ----------------
__global__ __launch_bounds__(512) void whz_init(
    const float* __restrict__ z0, const float* __restrict__ Wh, const float* __restrict__ bh,
    float* __restrict__ Whz0)
{
    const int t   = threadIdx.x;
    const int rep = t & 7;
    const int d0  = t >> 3;
    float4 wh0[4], wh1[4];
    #pragma unroll
    for (int m = 0; m < 4; ++m) {
        wh0[m] = *(const float4*)(Wh + (size_t)d0*DD + rep*16 + m*4);
        wh1[m] = *(const float4*)(Wh + (size_t)(d0+64)*DD + rep*16 + m*4);
    }
    const float bh0 = bh[d0], bh1 = bh[d0+64];
    const int r0 = blockIdx.x * 16;
    for (int r = r0; r < r0 + 16; ++r) {
        const float* zr = z0 + (size_t)r*DD + rep*16;
        float a0 = 0.f, a1 = 0.f;
        #pragma unroll
        for (int m = 0; m < 4; ++m) {
            float4 zz = *(const float4*)(zr + m*4);
            a0 += dot4f(zz, wh0[m]);
            a1 += dot4f(zz, wh1[m]);
        }
        a0 += __shfl_xor(a0,1); a0 += __shfl_xor(a0,2); a0 += __shfl_xor(a0,4);
        a1 += __shfl_xor(a1,1); a1 += __shfl_xor(a1,2); a1 += __shfl_xor(a1,4);
        if (rep == 0) {
            Whz0[(size_t)r*DD + d0]    = a0 + bh0;
            Whz0[(size_t)r*DD + d0+64] = a1 + bh1;
        }
    }
}

// ---------------- last-update sources for u,v,neg rows ----------------
__global__ void src_kernel(const int* __restrict__ u, const int* __restrict__ v,
                           const int* __restrict__ neg,
                           int* __restrict__ zsrc, int* __restrict__ negsrc)
{
    const int i = blockIdx.x;
    const int k = threadIdx.x;
    if (k >= 2 + 2*QQ) return;
    const int n = (k == 0) ? u[i] : (k == 1) ? v[i] : neg[i*2*QQ + (k-2)];
    int s = n;
    for (int j = i-1; j >= 0; --j) {
        if (v[j] == n) { s = SRCF | (j*2 + 1); break; }
        if (u[j] == n) { s = SRCF | (j*2 + 0); break; }
    }
    if (k < 2) zsrc[i*2 + k] = s;
    else       negsrc[i*2*QQ + (k-2)] = s;
}

// ---------------- static-max + correction lists per (i,side) ----------------
__global__ void prep_kernel(const int* __restrict__ u, const int* __restrict__ v,
                            const int* __restrict__ nbr_cnt, const int2* __restrict__ nbr_pack,
                            const float* __restrict__ Whz0,
                            float* __restrict__ maxpre, int* __restrict__ ncorr,
                            int2* __restrict__ corr_pack)
{
    __shared__ int   su[BB], sv[BB];
    __shared__ int   sidx[MAXDEG];
    __shared__ float sq[MAXDEG];
    __shared__ unsigned char cflag[MAXDEG];
    __shared__ int ccnt;

    const int p   = blockIdx.x;
    const int i   = p >> 1;
    const int tid = threadIdx.x;
    if (tid < BB) { su[tid] = u[tid]; sv[tid] = v[tid]; }
    if (tid == 0) ccnt = 0;
    const int cnt = nbr_cnt[p];
    for (int jj = tid; jj < cnt; jj += 128) {
        int2 pk = nbr_pack[p*MAXDEG + jj];
        sidx[jj] = pk.x; sq[jj] = __int_as_float(pk.y);
    }
    __syncthreads();
    for (int jj = tid; jj < cnt; jj += 128) {
        const int r = sidx[jj];
        int fs = -1;
        for (int j = i-1; j >= 0; --j) {
            if (sv[j] == r) { fs = j*2 + 1; break; }
            if (su[j] == r) { fs = j*2 + 0; break; }
        }
        if (fs >= 0) {
            const int pos = atomicAdd(&ccnt, 1);   // order-free (commutative max fold)
            int2 cp; cp.x = fs; cp.y = __float_as_int(sq[jj]);
            corr_pack[p*MAXDEG + pos] = cp;
            cflag[jj] = 1;
        } else cflag[jj] = 0;
    }
    __syncthreads();
    const int d = tid;
    float m = -3.0e38f;
    for (int jj = 0; jj < cnt; ++jj)
        if (!cflag[jj]) m = fmaxf(m, sq[jj] * Whz0[(size_t)sidx[jj]*DD + d]);
    maxpre[(size_t)p*DD + d] = m;
    if (tid == 0) ncorr[p] = ccnt;
}

// ---------------- pair dependency flags ----------------
__global__ void pair_kernel(const int* __restrict__ zsrc, const int* __restrict__ ncorr,
                            const int2* __restrict__ corr_pack, int* __restrict__ pdep)
{
    const int g = blockIdx.x;
    const int tid = threadIdx.x;
    const int Astep = 2*g, Bstep = 2*g+1;
    __shared__ int dep;
    if (tid == 0) dep = 0;
    __syncthreads();
    if (tid < 2) {
        const int s = zsrc[Bstep*2 + tid];
        if ((s & SRCF) && (((s & 0xFFFF) >> 1) == Astep)) atomicOr(&dep, 1);
    }
    for (int k = 0; k < 2; ++k) {
        const int p = Bstep*2 + k;
        const int nc = ncorr[p];
        for (int c = tid; c < nc; c += 64)
            if ((corr_pack[p*MAXDEG + c].x >> 1) == Astep) atomicOr(&dep, 1);
    }
    __syncthreads();
    if (tid == 0) pdep[g] = dep;
}

// ---------------- sequential scan: 64 paired groups, conflict-free operand LDS ----------------
__global__ __launch_bounds__(512) void scan_kernel(
    const float* __restrict__ z0, const float* __restrict__ time_diff,
    const int* __restrict__ nbr_cnt, const int* __restrict__ ncorr,
    const int2* __restrict__ corr_pack,
    const float* __restrict__ maxpre, const int* __restrict__ zsrc,
    const int* __restrict__ pdep,
    const float* __restrict__ Wh,  const float* __restrict__ bh,
    const float* __restrict__ Wst, const float* __restrict__ bst,
    const float* __restrict__ Wrc, const float* __restrict__ brc,
    const float* __restrict__ Wt,  const float* __restrict__ bt,
    float* __restrict__ zlog)
{
    __shared__ __align__(16) unsigned short whz_sb[2*BB*DD];   // 64 KB whz log (bf16)
    __shared__ __align__(16) unsigned short zlog_sb[2*BB*DD];  // 64 KB z log (bf16)
    __shared__ __align__(16) unsigned short h_b[4][HP];        // padded: rows +4 banks
    __shared__ __align__(16) unsigned short zrow_b[4][HP];
    __shared__ __align__(16) unsigned short zupdb[4][HP];
    __shared__ __align__(16) float zupd_s[4][FP];
    __shared__ __align__(16) float tdw_s[4][FP];
    __shared__ __align__(16) float tdi_s[BB*8];
    __shared__ int cnt_s[2*BB], ncorr_s[2*BB], zsrc_s[2*BB];
    __shared__ int pdep_s[BB/2];
    __shared__ int defflag[4];

    const int t    = threadIdx.x;
    const int wv   = t >> 6;
    const int ln   = t & 63;
    const int arow = wv*16 + (ln & 15);
    const int kgrp = ln >> 4;
    const int ncol = ln & 15;
    const int dbase = wv*16 + kgrp*4;

    // ---- persistent A-fragments (packed bf16 -> remat-proof) ----
    bf16x8 afw[8];   // [Wst | Wrc], K=256
    #pragma unroll
    for (int kt = 0; kt < 8; ++kt) {
        const int kb = kt*32 + kgrp*8;
        const float* src = (kb < 128) ? (Wst + (size_t)arow*DD + kb)
                                      : (Wrc + (size_t)arow*DD + (kb - 128));
        #pragma unroll
        for (int j = 0; j < 8; ++j) afw[kt][j] = (short)bfr(src[j]);
    }
    bf16x8 afh[4];   // Wh, K=128
    #pragma unroll
    for (int kt = 0; kt < 4; ++kt) {
        const float* src = Wh + (size_t)arow*DD + kt*32 + kgrp*8;
        #pragma unroll
        for (int j = 0; j < 8; ++j) afh[kt][j] = (short)bfr(src[j]);
    }
    f32x4 bsv, bhv;
    #pragma unroll
    for (int r = 0; r < 4; ++r) {
        bsv[r] = bst[dbase+r] + brc[dbase+r] + bt[dbase+r];
        bhv[r] = bh[dbase+r];
    }
    const float4 wtA = *(const float4*)(Wt + (size_t)(ln*2)*4);
    const float4 wtB = *(const float4*)(Wt + (size_t)(ln*2+1)*4);

    // ---- one-time LDS preloads ----
    if (t < 256)      { cnt_s[t] = nbr_cnt[t]; ncorr_s[t] = ncorr[t]; }
    else              { zsrc_s[t-256] = zsrc[t-256]; }
    if (t < BB/2)     pdep_s[t] = pdep[t];
    if (t < 4)        defflag[t] = 0;
    {
        const float sdv[4] = {50.f, 7.f, 15.f, 15.f};
        for (int e = t; e < BB*8; e += 512) tdi_s[e] = time_diff[e] / sdv[e & 3];
    }
    __syncthreads();

    // ---- wave-private pipeline state ----
    float2 mwork = make_float2(0.f, 0.f);
    float2 mnext = make_float2(0.f, 0.f);
    int2 cpf0, cpf1, cpf2, cpf3;
    int2 de0, de1, de2, de3; int ndefr = 0;
    int2 ie0, ie1;           int nintra = 0;
    float2 zn2 = make_float2(0.f, 0.f);

    // ================= helper lambdas =================
    auto DO_P1 = [&]() {
        const int cc = (ncol < 4) ? ncol : 0;
        const unsigned short* hp = &h_b[cc][0];
        const unsigned short* zp = &zrow_b[cc][0];
        f32x4 accA = {0.f,0.f,0.f,0.f}, accB = {0.f,0.f,0.f,0.f};
        __builtin_amdgcn_s_setprio(1);
        #pragma unroll
        for (int kt = 0; kt < 4; kt += 2) {
            bf16x8 b0 = *(const bf16x8*)&hp[kt*32 + kgrp*8];
            bf16x8 b1 = *(const bf16x8*)&hp[(kt+1)*32 + kgrp*8];
            accA = __builtin_amdgcn_mfma_f32_16x16x32_bf16(afw[kt],   b0, accA, 0,0,0);
            accB = __builtin_amdgcn_mfma_f32_16x16x32_bf16(afw[kt+1], b1, accB, 0,0,0);
        }
        #pragma unroll
        for (int kt = 4; kt < 8; kt += 2) {
            bf16x8 b0 = *(const bf16x8*)&zp[(kt-4)*32 + kgrp*8];
            bf16x8 b1 = *(const bf16x8*)&zp[(kt-3)*32 + kgrp*8];
            accA = __builtin_amdgcn_mfma_f32_16x16x32_bf16(afw[kt],   b0, accA, 0,0,0);
            accB = __builtin_amdgcn_mfma_f32_16x16x32_bf16(afw[kt+1], b1, accB, 0,0,0);
        }
        __builtin_amdgcn_s_setprio(0);
        if (ncol < 4) {
            const f32x4 tdwv = *(const f32x4*)&tdw_s[ncol][dbase];
            f32x4 zu4;
            #pragma unroll
            for (int r = 0; r < 4; ++r) {
                const float a = accA[r] + accB[r] + bsv[r] + tdwv[r];
                zu4[r] = 1.0f/(1.0f + __expf(-a));
            }
            *(f32x4*)&zupd_s[ncol][dbase] = zu4;
            uint2 pk;
            pk.x = pack2bf(zu4[0], zu4[1]);
            pk.y = pack2bf(zu4[2], zu4[3]);
            *(uint2*)&zupdb[ncol][dbase] = pk;
        }
    };

    auto DO_P2 = [&](int writeAll, int G) {
        const int cc = (ncol < 4) ? ncol : 0;
        const unsigned short* up = &zupdb[cc][0];
        f32x4 accA = {0.f,0.f,0.f,0.f}, accB = {0.f,0.f,0.f,0.f};
        __builtin_amdgcn_s_setprio(1);
        {
            bf16x8 b0 = *(const bf16x8*)&up[0*32 + kgrp*8];
            bf16x8 b1 = *(const bf16x8*)&up[1*32 + kgrp*8];
            bf16x8 b2 = *(const bf16x8*)&up[2*32 + kgrp*8];
            bf16x8 b3 = *(const bf16x8*)&up[3*32 + kgrp*8];
            accA = __builtin_amdgcn_mfma_f32_16x16x32_bf16(afh[0], b0, accA, 0,0,0);
            accB = __builtin_amdgcn_mfma_f32_16x16x32_bf16(afh[1], b1, accB, 0,0,0);
            accA = __builtin_amdgcn_mfma_f32_16x16x32_bf16(afh[2], b2, accA, 0,0,0);
            accB = __builtin_amdgcn_mfma_f32_16x16x32_bf16(afh[3], b3, accB, 0,0,0);
        }
        __builtin_amdgcn_s_setprio(0);
        if (ncol < 4 && (writeAll || ncol < 2)) {
            const int row = 4*G + ncol;
            uint2 wpk;
            wpk.x = pack2bf(accA[0]+accB[0]+bhv[0], accA[1]+accB[1]+bhv[1]);
            wpk.y = pack2bf(accA[2]+accB[2]+bhv[2], accA[3]+accB[3]+bhv[3]);
            *(uint2*)&whz_sb[row*DD + dbase] = wpk;
            const f32x4 zu4 = *(const f32x4*)&zupd_s[ncol][dbase];
            uint2 zpk;
            zpk.x = pack2bf(zu4[0], zu4[1]);
            zpk.y = pack2bf(zu4[2], zu4[3]);
            *(uint2*)&zlog_sb[row*DD + dbase] = zpk;
        }
    };

    // Prepare pair curG+1 = steps {C, C+1}; classify corrections; publish what's ready.
    auto PREP = [&](int curG) {
        const int C = 2*curG + 2;
        if (C >= BB) return;
        if (wv < 4) {
            const int step = C + (wv >> 1);
            const int side = wv & 1;
            const int p1 = step*2 + side;
            const int nc = ncorr_s[p1];
            float2 m = mnext;
            int nd = 0, ni = 0;
            int2 dl0, dl1, dl2, dl3, il0, il1;
            auto FOLD = [&](int2 e) {
                if ((e.x >> 2) == curG) {                       // src in current pair -> defer
                    if (nd==0) dl0=e; else if (nd==1) dl1=e; else if (nd==2) dl2=e; else dl3=e;
                    ++nd;
                } else if ((e.x >> 1) == C && step == C+1) {    // intra-next-pair
                    if (ni==0) il0=e; else il1=e;
                    ++ni;
                } else {
                    const float qc = __int_as_float(e.y);
                    const unsigned pk = *(const unsigned*)&whz_sb[e.x*DD + ln*2];
                    m.x = fmaxf(m.x, qc * __uint_as_float(pk << 16));
                    m.y = fmaxf(m.y, qc * __uint_as_float(pk & 0xffff0000u));
                }
            };
            if (nc > 0) FOLD(cpf0);
            if (nc > 1) FOLD(cpf1);
            if (nc > 2) FOLD(cpf2);
            if (nc > 3) FOLD(cpf3);
            const int2* cpp = corr_pack + (size_t)p1*MAXDEG;
            for (int c = 4; c < nc; ++c) FOLD(cpp[c]);
            mwork = m; ndefr = nd; nintra = ni;
            de0=dl0; de1=dl1; de2=dl2; de3=dl3; ie0=il0; ie1=il1;
            if (nd == 0 && ni == 0) {
                float h0 = 0.f, h1 = 0.f;
                if (cnt_s[p1] > 0) {
                    h0 = 1.0f/(1.0f + __expf(-m.x));
                    h1 = 1.0f/(1.0f + __expf(-m.y));
                }
                *(unsigned*)&h_b[wv][ln*2] = pack2bf(h0, h1);
            }
            if (ln == 0) defflag[wv] = nd;
            const int Cn = C + 2;
            const int stepn = (Cn + (wv>>1) < BB) ? (Cn + (wv>>1)) : step;
            const int pn = stepn*2 + side;
            mnext = *(const float2*)&maxpre[(size_t)pn*DD + ln*2];
            const int2* cppn = corr_pack + (size_t)pn*MAXDEG;
            cpf0 = cppn[0]; cpf1 = cppn[1]; cpf2 = cppn[2]; cpf3 = cppn[3];
        } else {
            const int k = wv - 4;
            const int step = C + (k >> 1);
            const int uvk = k & 1;
            const int s = zsrc_s[step*2 + uvk];
            if (s & SRCF) {
                const int row = s & 0xFFFF;
                const int rg  = row >> 2;
                if (rg == curG) {
                    const float2 zf = *(const float2*)&zupd_s[row & 3][ln*2];
                    *(unsigned*)&zrow_b[k][ln*2] = pack2bf(zf.x, zf.y);
                } else if (rg < curG) {
                    *(unsigned*)&zrow_b[k][ln*2] = *(const unsigned*)&zlog_sb[row*DD + ln*2];
                }
                // rg == curG+1 (B references A of the NEXT pair): slow path republishes
            } else {
                *(unsigned*)&zrow_b[k][ln*2] = pack2bf(zn2.x, zn2.y);
            }
            if (wv == 4) {
                const float* tp = &tdi_s[C*8];
                tdw_s[0][ln*2]   = tp[0]*wtA.x + tp[1]*wtA.y + tp[2]*wtA.z + tp[3]*wtA.w;
                tdw_s[0][ln*2+1] = tp[0]*wtB.x + tp[1]*wtB.y + tp[2]*wtB.z + tp[3]*wtB.w;
                tdw_s[1][ln*2]   = tp[4]*wtA.x + tp[5]*wtA.y + tp[6]*wtA.z + tp[7]*wtA.w;
                tdw_s[1][ln*2+1] = tp[4]*wtB.x + tp[5]*wtB.y + tp[6]*wtB.z + tp[7]*wtB.w;
            } else if (wv == 5) {
                const float* tp = &tdi_s[(C+1)*8];
                tdw_s[2][ln*2]   = tp[0]*wtA.x + tp[1]*wtA.y + tp[2]*wtA.z + tp[3]*wtA.w;
                tdw_s[2][ln*2+1] = tp[0]*wtB.x + tp[1]*wtB.y + tp[2]*wtB.z + tp[3]*wtB.w;
                tdw_s[3][ln*2]   = tp[4]*wtA.x + tp[5]*wtA.y + tp[6]*wtA.z + tp[7]*wtA.w;
                tdw_s[3][ln*2+1] = tp[4]*wtB.x + tp[5]*wtB.y + tp[6]*wtB.z + tp[7]*wtB.w;
            }
            const int Cn = C + 2;
            if (Cn + (k>>1) < BB) {
                const int sn = zsrc_s[(Cn + (k>>1))*2 + uvk];
                if (!(sn & SRCF)) zn2 = *(const float2*)&z0[(size_t)sn*DD + ln*2];
            }
        }
    };

    // ---- priming: prefetch + prepare pair 0 ----
    if (wv < 4) {
        const int p0 = (wv >> 1)*2 + (wv & 1);
        mnext = *(const float2*)&maxpre[(size_t)p0*DD + ln*2];
        const int2* cpp = corr_pack + (size_t)p0*MAXDEG;
        cpf0 = cpp[0]; cpf1 = cpp[1]; cpf2 = cpp[2]; cpf3 = cpp[3];
    } else {
        const int k = wv - 4;
        const int s = zsrc_s[(k >> 1)*2 + (k & 1)];
        if (!(s & SRCF)) zn2 = *(const float2*)&z0[(size_t)s*DD + ln*2];
    }
    PREP(-1);
    LBAR();

    // ================= main loop over 64 pairs =================
    for (int G = 0; G < BB/2; ++G) {
        // ---- FIXUP: fold deferred cross-pair corrections ----
        if (defflag[0] | defflag[1] | defflag[2] | defflag[3]) {
            if (wv < 4 && ndefr) {
                float2 m = mwork;
                {
                    const float qc = __int_as_float(de0.y);
                    const unsigned pk = *(const unsigned*)&whz_sb[de0.x*DD + ln*2];
                    m.x = fmaxf(m.x, qc * __uint_as_float(pk << 16));
                    m.y = fmaxf(m.y, qc * __uint_as_float(pk & 0xffff0000u));
                }
                if (ndefr > 1) {
                    const float qc = __int_as_float(de1.y);
                    const unsigned pk = *(const unsigned*)&whz_sb[de1.x*DD + ln*2];
                    m.x = fmaxf(m.x, qc * __uint_as_float(pk << 16));
                    m.y = fmaxf(m.y, qc * __uint_as_float(pk & 0xffff0000u));
                }
                if (ndefr > 2) {
                    const float qc = __int_as_float(de2.y);
                    const unsigned pk = *(const unsigned*)&whz_sb[de2.x*DD + ln*2];
                    m.x = fmaxf(m.x, qc * __uint_as_float(pk << 16));
                    m.y = fmaxf(m.y, qc * __uint_as_float(pk & 0xffff0000u));
                }
                if (ndefr > 3) {
                    const float qc = __int_as_float(de3.y);
                    const unsigned pk = *(const unsigned*)&whz_sb[de3.x*DD + ln*2];
                    m.x = fmaxf(m.x, qc * __uint_as_float(pk << 16));
                    m.y = fmaxf(m.y, qc * __uint_as_float(pk & 0xffff0000u));
                }
                mwork = m; ndefr = 0;
                if (nintra == 0) {
                    const int p1 = (2*G + (wv>>1))*2 + (wv & 1);
                    float h0 = 0.f, h1 = 0.f;
                    if (cnt_s[p1] > 0) {
                        h0 = 1.0f/(1.0f + __expf(-m.x));
                        h1 = 1.0f/(1.0f + __expf(-m.y));
                    }
                    *(unsigned*)&h_b[wv][ln*2] = pack2bf(h0, h1);
                }
            }
            LBAR();
        }

        if (!pdep_s[G]) {
            // -------- fast path: 2 phases for 2 steps --------
            DO_P1();
            LBAR();
            DO_P2(1, G);
            PREP(G);
            LBAR();
        } else {
            // -------- slow path: step A then step B --------
            DO_P1();
            LBAR();
            DO_P2(0, G);
            if (wv >= 6) {
                const int k = wv - 4;
                const int s = zsrc_s[(2*G+1)*2 + (k & 1)];
                if ((s & SRCF) && (((s & 0xFFFF) >> 2) == G)) {
                    const int row = s & 0xFFFF;
                    const float2 zf = *(const float2*)&zupd_s[row & 3][ln*2];
                    *(unsigned*)&zrow_b[k][ln*2] = pack2bf(zf.x, zf.y);
                }
            }
            LBAR();
            if ((wv == 2 || wv == 3) && nintra) {
                float2 m = mwork;
                {
                    const float qc = __int_as_float(ie0.y);
                    const unsigned pk = *(const unsigned*)&whz_sb[ie0.x*DD + ln*2];
                    m.x = fmaxf(m.x, qc * __uint_as_float(pk << 16));
                    m.y = fmaxf(m.y, qc * __uint_as_float(pk & 0xffff0000u));
                }
                if (nintra > 1) {
                    const float qc = __int_as_float(ie1.y);
                    const unsigned pk = *(const unsigned*)&whz_sb[ie1.x*DD + ln*2];
                    m.x = fmaxf(m.x, qc * __uint_as_float(pk << 16));
                    m.y = fmaxf(m.y, qc * __uint_as_float(pk & 0xffff0000u));
                }
                const int p1 = (2*G+1)*2 + (wv & 1);
                float h0 = 0.f, h1 = 0.f;
                if (cnt_s[p1] > 0) {
                    h0 = 1.0f/(1.0f + __expf(-m.x));
                    h1 = 1.0f/(1.0f + __expf(-m.y));
                }
                *(unsigned*)&h_b[wv][ln*2] = pack2bf(h0, h1);
                nintra = 0;
            }
            LBAR();
            DO_P1();
            LBAR();
            DO_P2(1, G);
            PREP(G);
            LBAR();
        }
    }

    // ---- batched zlog dump (only global store in the kernel) ----
    for (int e = t; e < BB*DD; e += 512) {
        const unsigned pk = *(const unsigned*)&zlog_sb[e*2];
        float2 val;
        val.x = __uint_as_float(pk << 16);
        val.y = __uint_as_float(pk & 0xffff0000u);
        *(float2*)&zlog[(size_t)e*2] = val;
    }
}

// ---------------- intensity epilogue (parallel, reads via src indices) ----------------
__global__ void lam_kernel(const float* __restrict__ z0, const float* __restrict__ zlog,
                           const int* __restrict__ zsrc, const int* __restrict__ negsrc,
                           const int* __restrict__ et,
                           const float* __restrict__ w0, const float* __restrict__ b0,
                           const float* __restrict__ w1, const float* __restrict__ b1,
                           const float* __restrict__ psi,
                           float* __restrict__ out)
{
    const int b   = blockIdx.x;
    const int i   = b / 11;
    const int col = b % 11;
    const int l   = threadIdx.x;

    auto rp = [&](int s) -> const float* {
        return (s & SRCF) ? (zlog + (size_t)(s & 0xFFFF)*DD) : (z0 + (size_t)s*DD);
    };
    const float* xu;
    const float* xv;
    if (col == 0) { xu = rp(zsrc[i*2]); xv = rp(zsrc[i*2+1]); }
    else {
        const int k = col - 1;
        xu = (k < QQ) ? rp(zsrc[i*2])            : rp(negsrc[i*2*QQ + k]);
        xv = (k < QQ) ? rp(negsrc[i*2*QQ + k])   : rp(zsrc[i*2+1]);
    }
    float g0 = xu[l]*w0[l] + xu[l+64]*w0[l+64] + xv[l]*w0[DD+l] + xv[l+64]*w0[DD+l+64];
    float g1 = xu[l]*w1[l] + xu[l+64]*w1[l+64] + xv[l]*w1[DD+l] + xv[l+64]*w1[DD+l+64];
    #pragma unroll
    for (int s = 32; s >= 1; s >>= 1) { g0 += __shfl_xor(g0, s); g1 += __shfl_xor(g1, s); }
    if (l == 0) {
        g0 += b0[0]; g1 += b1[0];
        const float p0 = psi[0], p1 = psi[1];
        float r;
        if (col == 0) {
            const int e = et[i];
            const float g = e ? g1 : g0;
            const float p = e ? p1 : p0;
            const float y = g / (p + 1e-7f);
            r = p * (fmaxf(y, 0.f) + log1pf(expf(-fabsf(y))));
        } else {
            const float y0 = g0 / (p0 + 1e-7f);
            const float y1 = g1 / (p1 + 1e-7f);
            r = p0 * (fmaxf(y0, 0.f) + log1pf(expf(-fabsf(y0))))
              + p1 * (fmaxf(y1, 0.f) + log1pf(expf(-fabsf(y1))));
        }
        out[i*11 + col] = r;
    }
}

extern "C" void kernel_launch(void* const* d_in, const int* in_sizes, int n_in,
                              void* d_out, int out_size, void* d_ws, size_t ws_size,
                              hipStream_t stream)
{
    const int*   u   = (const int*)d_in[0];
    const int*   v   = (const int*)d_in[1];
    const int*   et  = (const int*)d_in[2];
    const float* td  = (const float*)d_in[3];
    const int*   neg = (const int*)d_in[4];
    const float* z0  = (const float*)d_in[5];
    const float* A   = (const float*)d_in[6];
    const float* S   = (const float*)d_in[7];
    const float* w0  = (const float*)d_in[8];
    const float* b0  = (const float*)d_in[9];
    const float* w1  = (const float*)d_in[10];
    const float* b1  = (const float*)d_in[11];
    const float* psi = (const float*)d_in[12];
    const float* Wh  = (const float*)d_in[13];
    const float* bh  = (const float*)d_in[14];
    const float* Wst = (const float*)d_in[15];
    const float* bst = (const float*)d_in[16];
    const float* Wrc = (const float*)d_in[17];
    const float* brc = (const float*)d_in[18];
    const float* Wt  = (const float*)d_in[19];
    const float* bt  = (const float*)d_in[20];

    char* ws = (char*)d_ws;
    size_t off = 0;
    auto alloc = [&](size_t bytes) {
        void* p = ws + off;
        off = (off + bytes + 255) & ~(size_t)255;
        return p;
    };
    float* Whz0   = (float*)alloc((size_t)NN*DD*sizeof(float));
    float* maxpre = (float*)alloc((size_t)2*BB*DD*sizeof(float));
    float* zlog   = (float*)alloc((size_t)2*BB*DD*sizeof(float));
    int*   ncnt   = (int*)alloc((size_t)2*BB*sizeof(int));
    int*   ncorr  = (int*)alloc((size_t)2*BB*sizeof(int));
    int2*  cpk    = (int2*)alloc((size_t)2*BB*MAXDEG*sizeof(int2));
    int*   zsrc   = (int*)alloc((size_t)2*BB*sizeof(int));
    int*   negsrc = (int*)alloc((size_t)BB*2*QQ*sizeof(int));
    int*   pdep   = (int*)alloc((size_t)(BB/2)*sizeof(int));
    int2*  npk    = (int2*)alloc((size_t)2*BB*MAXDEG*sizeof(int2));

    whz_init<<<NN/16, 512, 0, stream>>>(z0, Wh, bh, Whz0);
    nbr_kernel<<<2*BB, 256, 0, stream>>>(u, v, A, S, ncnt, npk);
    src_kernel<<<BB, 64, 0, stream>>>(u, v, neg, zsrc, negsrc);
    prep_kernel<<<2*BB, 128, 0, stream>>>(u, v, ncnt, npk, Whz0, maxpre, ncorr, cpk);
    pair_kernel<<<BB/2, 64, 0, stream>>>(zsrc, ncorr, cpk, pdep);
    scan_kernel<<<1, 512, 0, stream>>>(z0, td, ncnt, ncorr, cpk, maxpre, zsrc, pdep,
                                       Wh, bh, Wst, bst, Wrc, brc, Wt, bt, zlog);
    lam_kernel<<<BB*(1 + 2*QQ), 64, 0, stream>>>(z0, zlog, zsrc, negsrc, et,
                                                 w0, b0, w1, b1, psi, (float*)d_out);
}